// Round 9
// baseline (512.656 us; speedup 1.0000x reference)
//
#include <hip/hip_runtime.h>
#include <math.h>

namespace {

constexpr int NB   = 8;
constexpr int IMG  = 128;
constexpr float SCALE = 0.14433756729740643f; // 1/sqrt(48)

// frag-major bf16 weight buffer offsets (ushort elements)
constexpr int O_QKV = 0;          // 4*9*6*512   = 110592 (LN1-gamma folded)
constexpr int O_WP  = 110592;     // 4*12*2*512  =  49152 (per-head, k-padded to 64)
constexpr int O_W1  = 159744;     // 48*6*512    = 147456 (LN2-gamma folded)
constexpr int O_W2  = 307200;     // 12*24*512   = 147456
constexpr int W_TOT = 454656;     // ushorts -> float region at byte 909312
// float region: CS0[576], K0[576], CS1[768], K1[768]

constexpr int HSTR = 136;         // MLP hidden LDS stride (128 cols + pad)

typedef __bf16 bf16x8 __attribute__((ext_vector_type(8)));
typedef float  f32x4  __attribute__((ext_vector_type(4)));

__device__ __forceinline__ unsigned short f2b(float f) {
    union { __bf16 h; unsigned short u; } c;
    c.h = (__bf16)f;                      // v_cvt_pk_bf16_f32 on gfx950 (RTNE)
    return c.u;
}
__device__ __forceinline__ float b2f(unsigned short h) {
    union { unsigned int u; float f; } a; a.u = ((unsigned int)h) << 16;
    return a.f;
}
__device__ __forceinline__ bf16x8 ldfrag(const unsigned short* p) {
    return *reinterpret_cast<const bf16x8*>(p);
}
__device__ __forceinline__ f32x4 MFMA(bf16x8 a, bf16x8 b, f32x4 c) {
    return __builtin_amdgcn_mfma_f32_16x16x32_bf16(a, b, c, 0, 0, 0);
}
__device__ __forceinline__ int token_region(int wh, int ww, int tok) {
    const int hh = wh * 8 + (tok >> 3);
    const int wp = ww * 8 + (tok & 7);
    const int hr = (hh < IMG - 8) ? 0 : ((hh < IMG - 4) ? 1 : 2);
    const int wr = (wp < IMG - 8) ? 0 : ((wp < IMG - 4) ? 1 : 2);
    return hr * 3 + wr;
}
__device__ __forceinline__ float gelu_f(float v) {
    float y = 1.5957691216057308f * (v + 0.044715f * v * v * v);
    y = fminf(fmaxf(y, -40.f), 40.f);
    const float e = __expf(y);
    const float t = (e - 1.f) * __builtin_amdgcn_rcpf(e + 1.f);
    return 0.5f * v * (1.f + t);
}
__device__ __forceinline__ void unpack8(uint4 r, float* v) {
    v[0] = b2f((unsigned short)(r.x & 0xFFFF)); v[1] = b2f((unsigned short)(r.x >> 16));
    v[2] = b2f((unsigned short)(r.y & 0xFFFF)); v[3] = b2f((unsigned short)(r.y >> 16));
    v[4] = b2f((unsigned short)(r.z & 0xFFFF)); v[5] = b2f((unsigned short)(r.z >> 16));
    v[6] = b2f((unsigned short)(r.w & 0xFFFF)); v[7] = b2f((unsigned short)(r.w >> 16));
}

// ---- weights -> bf16 frag-major (LN gammas folded into QKV / W1) ----
__global__ __launch_bounds__(256)
void convert_frag(const float* __restrict__ qkv_w, const float* __restrict__ proj_w,
                  const float* __restrict__ w1, const float* __restrict__ w2,
                  const float* __restrict__ n1g, const float* __restrict__ n2g,
                  unsigned short* __restrict__ wf)
{
    const int id = blockIdx.x * 256 + threadIdx.x;
    if (id >= W_TOT) return;
    float val;
    if (id < O_WP) {
        const int j = id & 7, l = (id >> 3) & 63, rem = id >> 9;
        const int ks = rem % 6, n = (rem / 6) % 9, h = rem / 54;
        const int k = ks * 32 + (l >> 4) * 8 + j;
        const int scol = n * 16 + (l & 15);
        const int col = (scol / 48) * 192 + h * 48 + scol % 48;
        val = qkv_w[k * 576 + col] * n1g[k];
    } else if (id < O_W1) {
        const int t = id - O_WP;
        const int j = t & 7, l = (t >> 3) & 63, rem = t >> 9;   // 0..95
        const int ks = rem % 2, tt = (rem / 2) % 12, h = rem / 24;
        const int k = ks * 32 + (l >> 4) * 8 + j;               // padded-d 0..63
        const int col = tt * 16 + (l & 15);
        val = (k < 48) ? proj_w[(h * 48 + k) * 192 + col] : 0.f;
    } else if (id < O_W2) {
        const int t = id - O_W1;
        const int j = t & 7, l = (t >> 3) & 63, rem = t >> 9;
        const int ks = rem % 6, n = rem / 6;
        const int k = ks * 32 + (l >> 4) * 8 + j;
        val = w1[k * 768 + n * 16 + (l & 15)] * n2g[k];
    } else {
        const int t = id - O_W2;
        const int j = t & 7, l = (t >> 3) & 63, rem = t >> 9;
        const int ks = rem % 24, n = rem / 24;
        const int k = ks * 32 + (l >> 4) * 8 + j;
        val = w2[k * 192 + n * 16 + (l & 15)];
    }
    wf[id] = f2b(val);
}

// ---- column sums + folded bias constants (fp32) ----
__global__ __launch_bounds__(256)
void convert_vec(const float* __restrict__ qkv_w, const float* __restrict__ qkv_b,
                 const float* __restrict__ n1g, const float* __restrict__ n1b,
                 const float* __restrict__ w1, const float* __restrict__ b1,
                 const float* __restrict__ n2g, const float* __restrict__ n2b,
                 float* __restrict__ fbuf)
{
    const int id = blockIdx.x * 256 + threadIdx.x;
    if (id < 576) {
        const int li = id & 15, n = (id >> 4) % 9, h = id / 144;
        const int scol = n * 16 + li;
        const int col = (scol / 48) * 192 + h * 48 + scol % 48;
        float cs = 0.f, k0 = 0.f;
        for (int c = 0; c < 192; ++c) {
            const float wv = qkv_w[c * 576 + col];
            cs += n1g[c] * wv; k0 += n1b[c] * wv;
        }
        fbuf[id] = cs;
        fbuf[576 + id] = k0 + qkv_b[col];
    } else if (id < 1344) {
        const int u = id - 576;
        float cs = 0.f, k1 = 0.f;
        for (int c = 0; c < 192; ++c) {
            const float wv = w1[c * 768 + u];
            cs += n2g[c] * wv; k1 += n2b[c] * wv;
        }
        fbuf[1152 + u] = cs;
        fbuf[1920 + u] = k1 + b1[u];
    }
}

// LN stats via intra-wave shuffles: sPQ[row]=rsig, sPQ[64+row]=rsig*mu
__device__ __forceinline__ void stats_pass(const unsigned short* src, float* sPQ, int tid)
{
    const int w = tid >> 6, l = tid & 63;
    const int srow = 16 * w + (l >> 2);
    const int sub = l & 3;
    const unsigned short* sp = src + srow * 200 + sub * 48;
    float s = 0.f, s2 = 0.f;
    #pragma unroll
    for (int i = 0; i < 6; ++i) {
        uint4 r = *reinterpret_cast<const uint4*>(sp + i * 8);
        float v[8]; unpack8(r, v);
        #pragma unroll
        for (int e = 0; e < 8; ++e) { s += v[e]; s2 += v[e] * v[e]; }
    }
    s  += __shfl_xor(s, 1);  s  += __shfl_xor(s, 2);
    s2 += __shfl_xor(s2, 1); s2 += __shfl_xor(s2, 2);
    if (sub == 0) {
        const float mu = s * (1.f / 192.f);
        const float ms = s2 * (1.f / 192.f);
        const float rsig = rsqrtf(ms - mu * mu + 1e-5f);
        sPQ[srow] = rsig;
        sPQ[64 + srow] = rsig * mu;
    }
}

// Target: 3 waves/EU (total arch+acc <= 168). acc peak = MLP1 (ha 32 + ma 48 = 80).
__global__ __launch_bounds__(256, 3)
void swin_mfma(const float* __restrict__ x,
               const float* __restrict__ bias_tab,
               const float* __restrict__ proj_b,
               const float* __restrict__ b2,
               const unsigned short* __restrict__ wf,
               float* __restrict__ out)
{
    __shared__ unsigned short sB[64 * 200];   // x -> x1 -> x2 (bf16)
    __shared__ unsigned short sH[13440];      // q[64][72] | k[64][72] | vt[48][88]; hidden[64][HSTR]
    __shared__ float sPQ[128];                // rsig | rsig*mu per row

    constexpr int Q0  = 0;
    constexpr int K0o = 4608;
    constexpr int VT0 = 9216;

    const float* CS0f = reinterpret_cast<const float*>(wf + W_TOT);
    const float* K0f  = CS0f + 576;
    const float* CS1f = CS0f + 1152;
    const float* K1f  = CS0f + 1920;

    const int tid = threadIdx.x;
    const int l   = tid & 63;
    const int w   = tid >> 6;
    const int g   = l >> 4;
    const int li  = l & 15;

    const int wid  = blockIdx.x;
    const int b    = wid >> 8;
    const int nwin = wid & 255;
    const int wh   = nwin >> 4, ww = nwin & 15;

    // ---- zero-pad q,k cols 48..63 (persist through all heads) ----
    #pragma unroll
    for (int i = 0; i < 8; ++i) {
        const int e = i * 256 + tid;           // < 2048
        const int a = e >> 10;
        const int r = (e & 1023) >> 4;
        const int c = 48 + (e & 15);
        sH[(a ? K0o : Q0) + r * 72 + c] = 0;
    }

    // ---- vectorized load of shifted window -> sB (bf16) ----
    #pragma unroll
    for (int i = 0; i < 12; ++i) {
        const int id = i * 256 + tid;          // 0..3071
        const int c  = id >> 4;
        const int r  = (id >> 1) & 7;
        const int hf = id & 1;
        const int ohr = (wh * 8 + r + 4) & 127;
        const int owp = (ww * 8 + hf * 4 + 4) & 127;
        const float4 v = *reinterpret_cast<const float4*>(
            x + ((b * 192 + c) << 14) + (ohr << 7) + owp);
        const int t0 = r * 8 + hf * 4;
        sB[(t0 + 0) * 200 + c] = f2b(v.x);
        sB[(t0 + 1) * 200 + c] = f2b(v.y);
        sB[(t0 + 2) * 200 + c] = f2b(v.z);
        sB[(t0 + 3) * 200 + c] = f2b(v.w);
    }
    __syncthreads();

    // ---- LN1 stats ----
    stats_pass(sB, sPQ, tid);
    __syncthreads();

    // ---- hoisted attention lane constants ----
    const int qtok = 16 * w + li;
    const int qy = qtok >> 3, qx = qtok & 7;
    const int rq = token_region(wh, ww, qtok);
    unsigned int maskb = 0;
    unsigned int bpack[4];
    #pragma unroll
    for (int mt = 0; mt < 4; ++mt) {
        unsigned int pk = 0;
        #pragma unroll
        for (int ri = 0; ri < 4; ++ri) {
            const int k = mt * 16 + g * 4 + ri;
            const int ky = k >> 3, kx = k & 7;
            pk |= (unsigned int)((qy - ky + 7) * 15 + (qx - kx + 7)) << (8 * ri);
            if (token_region(wh, ww, k) != rq) maskb |= 1u << (mt * 4 + ri);
        }
        bpack[mt] = pk;
    }

    // packed attn-out^T per head: opk[h][mt*2+half] (bf16 pairs), static after unroll
    unsigned int opk[4][6];

    // ================= attention heads (fully unrolled: opk static) =================
    #pragma unroll
    for (int h = 0; h < 4; ++h) {
        // ---- P1: QKV GEMM (LN folded). Wave w owns output rows 16w..16w+15, all 9 N-tiles ----
        {
            f32x4 acc[9];
            #pragma unroll
            for (int n = 0; n < 9; ++n) acc[n] = (f32x4)0.f;
            #pragma unroll
            for (int ks = 0; ks < 6; ++ks) {
                bf16x8 af = ldfrag(&sB[(16 * w + li) * 200 + ks * 32 + g * 8]);
                #pragma unroll
                for (int n = 0; n < 9; ++n) {
                    bf16x8 bf = ldfrag(&wf[O_QKV + (((h * 9 + n) * 6 + ks) << 9) + l * 8]);
                    acc[n] = MFMA(af, bf, acc[n]);
                }
            }
            float pr[4], qr[4];
            #pragma unroll
            for (int ri = 0; ri < 4; ++ri) {
                pr[ri] = sPQ[16 * w + g * 4 + ri];
                qr[ri] = sPQ[64 + 16 * w + g * 4 + ri];
            }
            #pragma unroll
            for (int n = 0; n < 9; ++n) {
                const float csv = CS0f[(h * 9 + n) * 16 + li];
                const float k0v = K0f[(h * 9 + n) * 16 + li];
                const int arr = n / 3;             // 0=q 1=k 2=v (compile-time per n)
                const int d0 = (n % 3) * 16;       // d = d0 + li
                float val[4];
                #pragma unroll
                for (int ri = 0; ri < 4; ++ri)
                    val[ri] = pr[ri] * acc[n][ri] - qr[ri] * csv + k0v;
                if (arr < 2) {
                    unsigned short* dst = &sH[arr ? K0o : Q0];
                    #pragma unroll
                    for (int ri = 0; ri < 4; ++ri)
                        dst[(16 * w + g * 4 + ri) * 72 + d0 + li] = f2b(val[ri]);
                } else {
                    uint2 u;
                    u.x = (unsigned int)f2b(val[0]) | ((unsigned int)f2b(val[1]) << 16);
                    u.y = (unsigned int)f2b(val[2]) | ((unsigned int)f2b(val[3]) << 16);
                    *reinterpret_cast<uint2*>(&sH[VT0 + (d0 + li) * 88 + 16 * w + g * 4]) = u;
                }
            }
        }
        __syncthreads();

        // ---- P2: QK^T + register softmax + PV; out^T packed into opk[h] ----
        {
            f32x4 sc[4];
            #pragma unroll
            for (int mt = 0; mt < 4; ++mt) sc[mt] = (f32x4)0.f;
            #pragma unroll
            for (int ks = 0; ks < 2; ++ks) {
                bf16x8 bq = ldfrag(&sH[Q0 + qtok * 72 + ks * 32 + g * 8]);
                #pragma unroll
                for (int mt = 0; mt < 4; ++mt) {
                    bf16x8 ak = ldfrag(&sH[K0o + (mt * 16 + li) * 72 + ks * 32 + g * 8]);
                    sc[mt] = MFMA(ak, bq, sc[mt]);   // S^T = K @ Q^T
                }
            }
            float p[4][4];
            float m = -3.0e38f;
            #pragma unroll
            for (int mt = 0; mt < 4; ++mt)
                #pragma unroll
                for (int ri = 0; ri < 4; ++ri) {
                    const int bit = mt * 4 + ri;
                    const float bv = ((maskb >> bit) & 1u) ? -100.f
                        : bias_tab[h * 225 + ((bpack[mt] >> (8 * ri)) & 255u)];
                    const float s = sc[mt][ri] * SCALE + bv;
                    p[mt][ri] = s;
                    m = fmaxf(m, s);
                }
            m = fmaxf(m, __shfl_xor(m, 16));
            m = fmaxf(m, __shfl_xor(m, 32));
            float rs = 0.f;
            #pragma unroll
            for (int mt = 0; mt < 4; ++mt)
                #pragma unroll
                for (int ri = 0; ri < 4; ++ri) {
                    const float e = __expf(p[mt][ri] - m);
                    p[mt][ri] = e; rs += e;
                }
            rs += __shfl_xor(rs, 16);
            rs += __shfl_xor(rs, 32);
            const float rcp = __builtin_amdgcn_rcpf(rs);

            f32x4 oa[3];
            #pragma unroll
            for (int mt = 0; mt < 3; ++mt) oa[mt] = (f32x4)0.f;
            #pragma unroll
            for (int ks = 0; ks < 2; ++ks) {
                union { unsigned short us[8]; bf16x8 v; } bp;
                #pragma unroll
                for (int jj = 0; jj < 8; ++jj) {
                    const int srcLane = li + 16 * (2 * (g & 1) + (jj >> 2));
                    const float va = __shfl(p[ks * 2 + 0][jj & 3], srcLane);
                    const float vb = __shfl(p[ks * 2 + 1][jj & 3], srcLane);
                    bp.us[jj] = f2b((g >> 1) ? vb : va);
                }
                #pragma unroll
                for (int mt = 0; mt < 3; ++mt) {
                    bf16x8 av = ldfrag(&sH[VT0 + (mt * 16 + li) * 88 + ks * 32 + g * 8]);
                    oa[mt] = MFMA(av, bp.v, oa[mt]);  // out^T = Vt @ P^T
                }
            }
            #pragma unroll
            for (int mt = 0; mt < 3; ++mt) {
                opk[h][mt * 2 + 0] = (unsigned int)f2b(oa[mt][0] * rcp)
                                   | ((unsigned int)f2b(oa[mt][1] * rcp) << 16);
                opk[h][mt * 2 + 1] = (unsigned int)f2b(oa[mt][2] * rcp)
                                   | ((unsigned int)f2b(oa[mt][3] * rcp) << 16);
            }
        }
        __syncthreads();
    }

    // ---- proj GEMM in registers: wave w computes rows 16w..16w+15, all 192 cols ----
    f32x4 pa[12];
    #pragma unroll
    for (int tt = 0; tt < 12; ++tt) pa[tt] = (f32x4)0.f;
    #pragma unroll
    for (int h = 0; h < 4; ++h) {
        // assemble A-frags: a0 = d 0..31, a1 = d 32..63 (real d<48); row = li (qtok 16w+li)
        union { unsigned short us[8]; bf16x8 v; } a0, a1;
        #pragma unroll
        for (int j = 0; j < 8; ++j) {
            const int srcL = (((2 * g + (j >> 2)) & 3) << 4) + li;
            const int ih = (j & 3) >> 1;
            const int sh = 16 * (j & 1);
            const unsigned int v0 = __shfl(opk[h][0 + ih], srcL); // mt=0 (d 0..15)
            const unsigned int v1 = __shfl(opk[h][2 + ih], srcL); // mt=1 (d 16..31)
            const unsigned int v2 = __shfl(opk[h][4 + ih], srcL); // mt=2 (d 32..47)
            a0.us[j] = (unsigned short)((((g & 2) ? v1 : v0) >> sh) & 0xFFFFu);
            a1.us[j] = (g & 2) ? (unsigned short)0
                               : (unsigned short)((v2 >> sh) & 0xFFFFu);
        }
        #pragma unroll
        for (int tt = 0; tt < 12; ++tt) {
            bf16x8 w0 = ldfrag(&wf[O_WP + ((h * 24 + tt * 2 + 0) << 9) + l * 8]);
            bf16x8 w1f = ldfrag(&wf[O_WP + ((h * 24 + tt * 2 + 1) << 9) + l * 8]);
            pa[tt] = MFMA(a0.v, w0, pa[tt]);
            pa[tt] = MFMA(a1.v, w1f, pa[tt]);
        }
    }

    // ---- x1 = x + proj + proj_b (RMW sB; each element owned by one thread) ----
    #pragma unroll
    for (int tt = 0; tt < 12; ++tt) {
        const int col = tt * 16 + li;
        const float pbv = proj_b[col];
        #pragma unroll
        for (int ri = 0; ri < 4; ++ri) {
            const int o = (16 * w + g * 4 + ri) * 200 + col;
            sB[o] = f2b(b2f(sB[o]) + pa[tt][ri] + pbv);
        }
    }
    __syncthreads();

    // ---- LN2 stats ----
    stats_pass(sB, sPQ, tid);
    __syncthreads();

    // ---- MLP (LN2 folded into W1), hidden chunks of 128 (6 chunks): acc peak 80 ----
    f32x4 ma[3][4];
    #pragma unroll
    for (int tt = 0; tt < 3; ++tt)
        #pragma unroll
        for (int mt = 0; mt < 4; ++mt) ma[tt][mt] = (f32x4)0.f;

    for (int ch = 0; ch < 6; ++ch) {
        {
            f32x4 ha[2][4];
            #pragma unroll
            for (int tt = 0; tt < 2; ++tt)
                #pragma unroll
                for (int mt = 0; mt < 4; ++mt) ha[tt][mt] = (f32x4)0.f;
            #pragma unroll
            for (int ks = 0; ks < 6; ++ks) {
                bf16x8 af[4];
                #pragma unroll
                for (int mt = 0; mt < 4; ++mt)
                    af[mt] = ldfrag(&sB[(mt * 16 + li) * 200 + ks * 32 + g * 8]);
                #pragma unroll
                for (int tt = 0; tt < 2; ++tt) {
                    bf16x8 bf = ldfrag(&wf[O_W1 + (((ch * 8 + 2 * w + tt) * 6 + ks) << 9) + l * 8]);
                    #pragma unroll
                    for (int mt = 0; mt < 4; ++mt) ha[tt][mt] = MFMA(af[mt], bf, ha[tt][mt]);
                }
            }
            #pragma unroll
            for (int mt = 0; mt < 4; ++mt) {
                float pr[4], qr[4];
                #pragma unroll
                for (int ri = 0; ri < 4; ++ri) {
                    pr[ri] = sPQ[mt * 16 + g * 4 + ri];
                    qr[ri] = sPQ[64 + mt * 16 + g * 4 + ri];
                }
                #pragma unroll
                for (int tt = 0; tt < 2; ++tt) {
                    const int colL = (2 * w + tt) * 16 + li;   // 0..127 chunk-local
                    const float cs1 = CS1f[ch * 128 + colL];
                    const float k1v = K1f[ch * 128 + colL];
                    #pragma unroll
                    for (int ri = 0; ri < 4; ++ri) {
                        const float hv = pr[ri] * ha[tt][mt][ri] - qr[ri] * cs1 + k1v;
                        sH[(mt * 16 + g * 4 + ri) * HSTR + colL] = f2b(gelu_f(hv));
                    }
                }
            }
        }
        __syncthreads();
        #pragma unroll
        for (int ks = 0; ks < 4; ++ks) {           // K = 128 per chunk
            bf16x8 af[4];
            #pragma unroll
            for (int mt = 0; mt < 4; ++mt)
                af[mt] = ldfrag(&sH[(mt * 16 + li) * HSTR + ks * 32 + g * 8]);
            #pragma unroll
            for (int tt = 0; tt < 3; ++tt) {
                bf16x8 bf = ldfrag(&wf[O_W2 + (((3 * w + tt) * 24 + ch * 4 + ks) << 9) + l * 8]);
                #pragma unroll
                for (int mt = 0; mt < 4; ++mt) ma[tt][mt] = MFMA(af[mt], bf, ma[tt][mt]);
            }
        }
        __syncthreads();
    }

    // ---- x2 = x1 + mlp + b2 -> sB ----
    #pragma unroll
    for (int tt = 0; tt < 3; ++tt) {
        const int col = (3 * w + tt) * 16 + li;
        const float bv = b2[col];
        #pragma unroll
        for (int mt = 0; mt < 4; ++mt)
            #pragma unroll
            for (int ri = 0; ri < 4; ++ri) {
                const int o = (mt * 16 + g * 4 + ri) * 200 + col;
                sB[o] = f2b(ma[tt][mt][ri] + bv + b2f(sB[o]));
            }
    }
    __syncthreads();

    // ---- vectorized store (window reverse + roll back) ----
    #pragma unroll
    for (int i = 0; i < 12; ++i) {
        const int id = i * 256 + tid;
        const int c  = id >> 4;
        const int r  = (id >> 1) & 7;
        const int hf = id & 1;
        const int ohr = (wh * 8 + r + 4) & 127;
        const int owp = (ww * 8 + hf * 4 + 4) & 127;
        const int t0 = r * 8 + hf * 4;
        float4 v;
        v.x = b2f(sB[(t0 + 0) * 200 + c]);
        v.y = b2f(sB[(t0 + 1) * 200 + c]);
        v.z = b2f(sB[(t0 + 2) * 200 + c]);
        v.w = b2f(sB[(t0 + 3) * 200 + c]);
        *reinterpret_cast<float4*>(out + ((b * 192 + c) << 14) + (ohr << 7) + owp) = v;
    }
}

} // namespace

extern "C" void kernel_launch(void* const* d_in, const int* in_sizes, int n_in,
                              void* d_out, int out_size, void* d_ws, size_t ws_size,
                              hipStream_t stream) {
    (void)in_sizes; (void)n_in; (void)ws_size; (void)out_size;
    const float* x   = (const float*)d_in[0];
    const float* bt  = (const float*)d_in[1];
    const float* qw  = (const float*)d_in[2];
    const float* qb  = (const float*)d_in[3];
    const float* pw  = (const float*)d_in[4];
    const float* pb  = (const float*)d_in[5];
    const float* g1  = (const float*)d_in[6];
    const float* be1 = (const float*)d_in[7];
    const float* g2  = (const float*)d_in[8];
    const float* be2 = (const float*)d_in[9];
    const float* w1  = (const float*)d_in[10];
    const float* bb1 = (const float*)d_in[11];
    const float* w2  = (const float*)d_in[12];
    const float* bb2 = (const float*)d_in[13];

    unsigned short* wf = (unsigned short*)d_ws;
    float* fbuf = (float*)((char*)d_ws + (size_t)W_TOT * 2);

    convert_frag<<<(W_TOT + 255) / 256, 256, 0, stream>>>(qw, pw, w1, w2, g1, g2, wf);
    convert_vec<<<6, 256, 0, stream>>>(qw, qb, g1, be1, w1, bb1, g2, be2, fbuf);
    swin_mfma<<<NB * 256, 256, 0, stream>>>(x, bt, pb, bb2, wf, (float*)d_out);
}

// Round 10
// 452.565 us; speedup vs baseline: 1.1328x; 1.1328x over previous
//
#include <hip/hip_runtime.h>
#include <math.h>

namespace {

constexpr int NB   = 8;
constexpr int IMG  = 128;
constexpr float SCALE = 0.14433756729740643f; // 1/sqrt(48)

// frag-major bf16 weight buffer offsets (ushort elements)
constexpr int O_QKV = 0;          // 4*9*6*512   = 110592 (LN1-gamma folded)
constexpr int O_WP  = 110592;     // 4*12*2*512  =  49152 (per-head, k-padded to 64)
constexpr int O_W1  = 159744;     // 48*6*512    = 147456 (LN2-gamma folded)
constexpr int O_W2  = 307200;     // 12*24*512   = 147456
constexpr int W_TOT = 454656;     // ushorts -> float region at byte 909312
// float region: CS0[576], K0[576], CS1[768], K1[768]

constexpr int HSTR = 136;         // MLP hidden LDS stride (128 cols + pad)

typedef __bf16 bf16x8 __attribute__((ext_vector_type(8)));
typedef float  f32x4  __attribute__((ext_vector_type(4)));

__device__ __forceinline__ unsigned short f2b(float f) {
    union { __bf16 h; unsigned short u; } c;
    c.h = (__bf16)f;                      // native cvt, RTNE (absmax-verified r9)
    return c.u;
}
__device__ __forceinline__ float b2f(unsigned short h) {
    union { unsigned int u; float f; } a; a.u = ((unsigned int)h) << 16;
    return a.f;
}
__device__ __forceinline__ bf16x8 ldfrag(const unsigned short* p) {
    return *reinterpret_cast<const bf16x8*>(p);
}
__device__ __forceinline__ f32x4 MFMA(bf16x8 a, bf16x8 b, f32x4 c) {
    return __builtin_amdgcn_mfma_f32_16x16x32_bf16(a, b, c, 0, 0, 0);
}
__device__ __forceinline__ int token_region(int wh, int ww, int tok) {
    const int hh = wh * 8 + (tok >> 3);
    const int wp = ww * 8 + (tok & 7);
    const int hr = (hh < IMG - 8) ? 0 : ((hh < IMG - 4) ? 1 : 2);
    const int wr = (wp < IMG - 8) ? 0 : ((wp < IMG - 4) ? 1 : 2);
    return hr * 3 + wr;
}
__device__ __forceinline__ float gelu_f(float v) {
    float y = 1.5957691216057308f * (v + 0.044715f * v * v * v);
    y = fminf(fmaxf(y, -40.f), 40.f);
    const float e = __expf(y);
    const float t = (e - 1.f) * __builtin_amdgcn_rcpf(e + 1.f);
    return 0.5f * v * (1.f + t);
}
__device__ __forceinline__ void unpack8(uint4 r, float* v) {
    v[0] = b2f((unsigned short)(r.x & 0xFFFF)); v[1] = b2f((unsigned short)(r.x >> 16));
    v[2] = b2f((unsigned short)(r.y & 0xFFFF)); v[3] = b2f((unsigned short)(r.y >> 16));
    v[4] = b2f((unsigned short)(r.z & 0xFFFF)); v[5] = b2f((unsigned short)(r.z >> 16));
    v[6] = b2f((unsigned short)(r.w & 0xFFFF)); v[7] = b2f((unsigned short)(r.w >> 16));
}

// ---- weights -> bf16 frag-major (LN gammas folded into QKV / W1) ----
__global__ __launch_bounds__(256)
void convert_frag(const float* __restrict__ qkv_w, const float* __restrict__ proj_w,
                  const float* __restrict__ w1, const float* __restrict__ w2,
                  const float* __restrict__ n1g, const float* __restrict__ n2g,
                  unsigned short* __restrict__ wf)
{
    const int id = blockIdx.x * 256 + threadIdx.x;
    if (id >= W_TOT) return;
    float val;
    if (id < O_WP) {
        const int j = id & 7, l = (id >> 3) & 63, rem = id >> 9;
        const int ks = rem % 6, n = (rem / 6) % 9, h = rem / 54;
        const int k = ks * 32 + (l >> 4) * 8 + j;
        const int scol = n * 16 + (l & 15);
        const int col = (scol / 48) * 192 + h * 48 + scol % 48;
        val = qkv_w[k * 576 + col] * n1g[k];
    } else if (id < O_W1) {
        const int t = id - O_WP;
        const int j = t & 7, l = (t >> 3) & 63, rem = t >> 9;   // 0..95
        const int ks = rem % 2, tt = (rem / 2) % 12, h = rem / 24;
        const int k = ks * 32 + (l >> 4) * 8 + j;               // padded-d 0..63
        const int col = tt * 16 + (l & 15);
        val = (k < 48) ? proj_w[(h * 48 + k) * 192 + col] : 0.f;
    } else if (id < O_W2) {
        const int t = id - O_W1;
        const int j = t & 7, l = (t >> 3) & 63, rem = t >> 9;
        const int ks = rem % 6, n = rem / 6;
        const int k = ks * 32 + (l >> 4) * 8 + j;
        val = w1[k * 768 + n * 16 + (l & 15)] * n2g[k];
    } else {
        const int t = id - O_W2;
        const int j = t & 7, l = (t >> 3) & 63, rem = t >> 9;
        const int ks = rem % 24, n = rem / 24;
        const int k = ks * 32 + (l >> 4) * 8 + j;
        val = w2[k * 192 + n * 16 + (l & 15)];
    }
    wf[id] = f2b(val);
}

// ---- column sums + folded bias constants (fp32) ----
__global__ __launch_bounds__(256)
void convert_vec(const float* __restrict__ qkv_w, const float* __restrict__ qkv_b,
                 const float* __restrict__ n1g, const float* __restrict__ n1b,
                 const float* __restrict__ w1, const float* __restrict__ b1,
                 const float* __restrict__ n2g, const float* __restrict__ n2b,
                 float* __restrict__ fbuf)
{
    const int id = blockIdx.x * 256 + threadIdx.x;
    if (id < 576) {
        const int li = id & 15, n = (id >> 4) % 9, h = id / 144;
        const int scol = n * 16 + li;
        const int col = (scol / 48) * 192 + h * 48 + scol % 48;
        float cs = 0.f, k0 = 0.f;
        for (int c = 0; c < 192; ++c) {
            const float wv = qkv_w[c * 576 + col];
            cs += n1g[c] * wv; k0 += n1b[c] * wv;
        }
        fbuf[id] = cs;
        fbuf[576 + id] = k0 + qkv_b[col];
    } else if (id < 1344) {
        const int u = id - 576;
        float cs = 0.f, k1 = 0.f;
        for (int c = 0; c < 192; ++c) {
            const float wv = w1[c * 768 + u];
            cs += n2g[c] * wv; k1 += n2b[c] * wv;
        }
        fbuf[1152 + u] = cs;
        fbuf[1920 + u] = k1 + b1[u];
    }
}

// LN stats via intra-wave shuffles: sPQ[row]=rsig, sPQ[64+row]=rsig*mu
__device__ __forceinline__ void stats_pass(const unsigned short* src, float* sPQ, int tid)
{
    const int w = tid >> 6, l = tid & 63;
    const int srow = 16 * w + (l >> 2);
    const int sub = l & 3;
    const unsigned short* sp = src + srow * 200 + sub * 48;
    float s = 0.f, s2 = 0.f;
    #pragma unroll
    for (int i = 0; i < 6; ++i) {
        uint4 r = *reinterpret_cast<const uint4*>(sp + i * 8);
        float v[8]; unpack8(r, v);
        #pragma unroll
        for (int e = 0; e < 8; ++e) { s += v[e]; s2 += v[e] * v[e]; }
    }
    s  += __shfl_xor(s, 1);  s  += __shfl_xor(s, 2);
    s2 += __shfl_xor(s2, 1); s2 += __shfl_xor(s2, 2);
    if (sub == 0) {
        const float mu = s * (1.f / 192.f);
        const float ms = s2 * (1.f / 192.f);
        const float rsig = rsqrtf(ms - mu * mu + 1e-5f);
        sPQ[srow] = rsig;
        sPQ[64 + srow] = rsig * mu;
    }
}

// 3 waves/EU target: acc peak = MLP1 (ha 32 + ma 48 = 80) <= 84-clamp.
// QKV uses the shared-B scheme (low B-frag traffic, r8-proven).
__global__ __launch_bounds__(256, 3)
void swin_mfma(const float* __restrict__ x,
               const float* __restrict__ bias_tab,
               const float* __restrict__ proj_b,
               const float* __restrict__ b2,
               const unsigned short* __restrict__ wf,
               float* __restrict__ out)
{
    __shared__ unsigned short sB[64 * 200];   // x -> x1 -> x2 (bf16)
    __shared__ unsigned short sH[13440];      // q[64][72] | k[64][72] | vt[48][88]; hidden[64][HSTR]
    __shared__ float sPQ[128];                // rsig | rsig*mu per row

    constexpr int Q0  = 0;
    constexpr int K0o = 4608;
    constexpr int VT0 = 9216;

    const float* CS0f = reinterpret_cast<const float*>(wf + W_TOT);
    const float* K0f  = CS0f + 576;
    const float* CS1f = CS0f + 1152;
    const float* K1f  = CS0f + 1920;

    const int tid = threadIdx.x;
    const int l   = tid & 63;
    const int w   = tid >> 6;
    const int g   = l >> 4;
    const int li  = l & 15;

    const int wid  = blockIdx.x;
    const int b    = wid >> 8;
    const int nwin = wid & 255;
    const int wh   = nwin >> 4, ww = nwin & 15;

    // ---- zero-pad q,k cols 48..63 (persist through all heads) ----
    #pragma unroll
    for (int i = 0; i < 8; ++i) {
        const int e = i * 256 + tid;           // < 2048
        const int a = e >> 10;
        const int r = (e & 1023) >> 4;
        const int c = 48 + (e & 15);
        sH[(a ? K0o : Q0) + r * 72 + c] = 0;
    }

    // ---- vectorized load of shifted window -> sB (bf16) ----
    #pragma unroll
    for (int i = 0; i < 12; ++i) {
        const int id = i * 256 + tid;          // 0..3071
        const int c  = id >> 4;
        const int r  = (id >> 1) & 7;
        const int hf = id & 1;
        const int ohr = (wh * 8 + r + 4) & 127;
        const int owp = (ww * 8 + hf * 4 + 4) & 127;
        const float4 v = *reinterpret_cast<const float4*>(
            x + ((b * 192 + c) << 14) + (ohr << 7) + owp);
        const int t0 = r * 8 + hf * 4;
        sB[(t0 + 0) * 200 + c] = f2b(v.x);
        sB[(t0 + 1) * 200 + c] = f2b(v.y);
        sB[(t0 + 2) * 200 + c] = f2b(v.z);
        sB[(t0 + 3) * 200 + c] = f2b(v.w);
    }
    __syncthreads();

    // ---- LN1 stats ----
    stats_pass(sB, sPQ, tid);
    __syncthreads();

    // ---- hoisted attention lane constants ----
    const int qtok = 16 * w + li;
    const int qy = qtok >> 3, qx = qtok & 7;
    const int rq = token_region(wh, ww, qtok);
    unsigned int maskb = 0;
    unsigned int bpack[4];
    #pragma unroll
    for (int mt = 0; mt < 4; ++mt) {
        unsigned int pk = 0;
        #pragma unroll
        for (int ri = 0; ri < 4; ++ri) {
            const int k = mt * 16 + g * 4 + ri;
            const int ky = k >> 3, kx = k & 7;
            pk |= (unsigned int)((qy - ky + 7) * 15 + (qx - kx + 7)) << (8 * ri);
            if (token_region(wh, ww, k) != rq) maskb |= 1u << (mt * 4 + ri);
        }
        bpack[mt] = pk;
    }

    // packed attn-out^T per head: opk[h][mt*2+half] (bf16 pairs), static after unroll
    unsigned int opk[4][6];

    // ================= attention heads (fully unrolled: opk static) =================
    #pragma unroll
    for (int h = 0; h < 4; ++h) {
        // ---- P1: QKV GEMM (LN folded), shared-B scheme: wave w owns N-tiles {w, 4+w, 8(w0)} ----
        {
            f32x4 acc[3][4];
            #pragma unroll
            for (int tt = 0; tt < 3; ++tt)
                #pragma unroll
                for (int mt = 0; mt < 4; ++mt) acc[tt][mt] = (f32x4)0.f;
            #pragma unroll
            for (int ks = 0; ks < 6; ++ks) {
                bf16x8 af[4];
                #pragma unroll
                for (int mt = 0; mt < 4; ++mt)
                    af[mt] = ldfrag(&sB[(mt * 16 + li) * 200 + ks * 32 + g * 8]);
                #pragma unroll
                for (int tt = 0; tt < 3; ++tt) {
                    if (tt == 2 && w != 0) continue;
                    const int n = (tt == 2) ? 8 : w + tt * 4;
                    bf16x8 bf = ldfrag(&wf[O_QKV + (((h * 9 + n) * 6 + ks) << 9) + l * 8]);
                    #pragma unroll
                    for (int mt = 0; mt < 4; ++mt) acc[tt][mt] = MFMA(af[mt], bf, acc[tt][mt]);
                }
            }
            float csv[3], k0v[3];
            #pragma unroll
            for (int tt = 0; tt < 3; ++tt) {
                if (tt == 2 && w != 0) { csv[tt] = 0.f; k0v[tt] = 0.f; continue; }
                const int n = (tt == 2) ? 8 : w + tt * 4;
                csv[tt] = CS0f[(h * 9 + n) * 16 + li];
                k0v[tt] = K0f[(h * 9 + n) * 16 + li];
            }
            #pragma unroll
            for (int mt = 0; mt < 4; ++mt) {
                float pr[4], qr[4];
                #pragma unroll
                for (int ri = 0; ri < 4; ++ri) {
                    pr[ri] = sPQ[mt * 16 + g * 4 + ri];
                    qr[ri] = sPQ[64 + mt * 16 + g * 4 + ri];
                }
                #pragma unroll
                for (int tt = 0; tt < 3; ++tt) {
                    if (tt == 2 && w != 0) continue;
                    const int n = (tt == 2) ? 8 : w + tt * 4;
                    const int scol0 = n * 16;
                    const int arr = scol0 / 48;      // wave-uniform
                    const int d0 = scol0 - arr * 48; // d = d0 + li
                    float val[4];
                    #pragma unroll
                    for (int ri = 0; ri < 4; ++ri)
                        val[ri] = pr[ri] * acc[tt][mt][ri] - qr[ri] * csv[tt] + k0v[tt];
                    if (arr < 2) {
                        unsigned short* dst = &sH[arr ? K0o : Q0];
                        #pragma unroll
                        for (int ri = 0; ri < 4; ++ri)
                            dst[(mt * 16 + g * 4 + ri) * 72 + d0 + li] = f2b(val[ri]);
                    } else {
                        uint2 u;
                        u.x = (unsigned int)f2b(val[0]) | ((unsigned int)f2b(val[1]) << 16);
                        u.y = (unsigned int)f2b(val[2]) | ((unsigned int)f2b(val[3]) << 16);
                        *reinterpret_cast<uint2*>(&sH[VT0 + (d0 + li) * 88 + mt * 16 + g * 4]) = u;
                    }
                }
            }
        }
        __syncthreads();

        // ---- P2: QK^T + register softmax + PV; out^T packed into opk[h] ----
        {
            f32x4 sc[4];
            #pragma unroll
            for (int mt = 0; mt < 4; ++mt) sc[mt] = (f32x4)0.f;
            #pragma unroll
            for (int ks = 0; ks < 2; ++ks) {
                bf16x8 bq = ldfrag(&sH[Q0 + qtok * 72 + ks * 32 + g * 8]);
                #pragma unroll
                for (int mt = 0; mt < 4; ++mt) {
                    bf16x8 ak = ldfrag(&sH[K0o + (mt * 16 + li) * 72 + ks * 32 + g * 8]);
                    sc[mt] = MFMA(ak, bq, sc[mt]);   // S^T = K @ Q^T
                }
            }
            float p[4][4];
            float m = -3.0e38f;
            #pragma unroll
            for (int mt = 0; mt < 4; ++mt)
                #pragma unroll
                for (int ri = 0; ri < 4; ++ri) {
                    const int bit = mt * 4 + ri;
                    const float bv = ((maskb >> bit) & 1u) ? -100.f
                        : bias_tab[h * 225 + ((bpack[mt] >> (8 * ri)) & 255u)];
                    const float s = sc[mt][ri] * SCALE + bv;
                    p[mt][ri] = s;
                    m = fmaxf(m, s);
                }
            m = fmaxf(m, __shfl_xor(m, 16));
            m = fmaxf(m, __shfl_xor(m, 32));
            float rs = 0.f;
            #pragma unroll
            for (int mt = 0; mt < 4; ++mt)
                #pragma unroll
                for (int ri = 0; ri < 4; ++ri) {
                    const float e = __expf(p[mt][ri] - m);
                    p[mt][ri] = e; rs += e;
                }
            rs += __shfl_xor(rs, 16);
            rs += __shfl_xor(rs, 32);
            const float rcp = __builtin_amdgcn_rcpf(rs);

            f32x4 oa[3];
            #pragma unroll
            for (int mt = 0; mt < 3; ++mt) oa[mt] = (f32x4)0.f;
            #pragma unroll
            for (int ks = 0; ks < 2; ++ks) {
                union { unsigned short us[8]; bf16x8 v; } bp;
                #pragma unroll
                for (int jj = 0; jj < 8; ++jj) {
                    const int srcLane = li + 16 * (2 * (g & 1) + (jj >> 2));
                    const float va = __shfl(p[ks * 2 + 0][jj & 3], srcLane);
                    const float vb = __shfl(p[ks * 2 + 1][jj & 3], srcLane);
                    bp.us[jj] = f2b((g >> 1) ? vb : va);
                }
                #pragma unroll
                for (int mt = 0; mt < 3; ++mt) {
                    bf16x8 av = ldfrag(&sH[VT0 + (mt * 16 + li) * 88 + ks * 32 + g * 8]);
                    oa[mt] = MFMA(av, bp.v, oa[mt]);  // out^T = Vt @ P^T
                }
            }
            #pragma unroll
            for (int mt = 0; mt < 3; ++mt) {
                opk[h][mt * 2 + 0] = (unsigned int)f2b(oa[mt][0] * rcp)
                                   | ((unsigned int)f2b(oa[mt][1] * rcp) << 16);
                opk[h][mt * 2 + 1] = (unsigned int)f2b(oa[mt][2] * rcp)
                                   | ((unsigned int)f2b(oa[mt][3] * rcp) << 16);
            }
        }
        __syncthreads();
    }

    // ---- proj GEMM in registers: wave w computes rows 16w..16w+15, all 192 cols ----
    f32x4 pa[12];
    #pragma unroll
    for (int tt = 0; tt < 12; ++tt) pa[tt] = (f32x4)0.f;
    #pragma unroll
    for (int h = 0; h < 4; ++h) {
        // assemble A-frags: a0 = d 0..31, a1 = d 32..63 (real d<48); row = li (qtok 16w+li)
        union { unsigned short us[8]; bf16x8 v; } a0, a1;
        #pragma unroll
        for (int j = 0; j < 8; ++j) {
            const int srcL = (((2 * g + (j >> 2)) & 3) << 4) + li;
            const int ih = (j & 3) >> 1;
            const int sh = 16 * (j & 1);
            const unsigned int v0 = __shfl(opk[h][0 + ih], srcL); // mt=0 (d 0..15)
            const unsigned int v1 = __shfl(opk[h][2 + ih], srcL); // mt=1 (d 16..31)
            const unsigned int v2 = __shfl(opk[h][4 + ih], srcL); // mt=2 (d 32..47)
            a0.us[j] = (unsigned short)((((g & 2) ? v1 : v0) >> sh) & 0xFFFFu);
            a1.us[j] = (g & 2) ? (unsigned short)0
                               : (unsigned short)((v2 >> sh) & 0xFFFFu);
        }
        #pragma unroll
        for (int tt = 0; tt < 12; ++tt) {
            bf16x8 w0 = ldfrag(&wf[O_WP + ((h * 24 + tt * 2 + 0) << 9) + l * 8]);
            bf16x8 w1f = ldfrag(&wf[O_WP + ((h * 24 + tt * 2 + 1) << 9) + l * 8]);
            pa[tt] = MFMA(a0.v, w0, pa[tt]);
            pa[tt] = MFMA(a1.v, w1f, pa[tt]);
        }
    }

    // ---- x1 = x + proj + proj_b (RMW sB; each element owned by one thread) ----
    #pragma unroll
    for (int tt = 0; tt < 12; ++tt) {
        const int col = tt * 16 + li;
        const float pbv = proj_b[col];
        #pragma unroll
        for (int ri = 0; ri < 4; ++ri) {
            const int o = (16 * w + g * 4 + ri) * 200 + col;
            sB[o] = f2b(b2f(sB[o]) + pa[tt][ri] + pbv);
        }
    }
    __syncthreads();

    // ---- LN2 stats ----
    stats_pass(sB, sPQ, tid);
    __syncthreads();

    // ---- MLP (LN2 folded into W1), hidden chunks of 128 (6 chunks): acc peak 80 ----
    f32x4 ma[3][4];
    #pragma unroll
    for (int tt = 0; tt < 3; ++tt)
        #pragma unroll
        for (int mt = 0; mt < 4; ++mt) ma[tt][mt] = (f32x4)0.f;

    for (int ch = 0; ch < 6; ++ch) {
        {
            f32x4 ha[2][4];
            #pragma unroll
            for (int tt = 0; tt < 2; ++tt)
                #pragma unroll
                for (int mt = 0; mt < 4; ++mt) ha[tt][mt] = (f32x4)0.f;
            #pragma unroll
            for (int ks = 0; ks < 6; ++ks) {
                bf16x8 af[4];
                #pragma unroll
                for (int mt = 0; mt < 4; ++mt)
                    af[mt] = ldfrag(&sB[(mt * 16 + li) * 200 + ks * 32 + g * 8]);
                #pragma unroll
                for (int tt = 0; tt < 2; ++tt) {
                    bf16x8 bf = ldfrag(&wf[O_W1 + (((ch * 8 + 2 * w + tt) * 6 + ks) << 9) + l * 8]);
                    #pragma unroll
                    for (int mt = 0; mt < 4; ++mt) ha[tt][mt] = MFMA(af[mt], bf, ha[tt][mt]);
                }
            }
            #pragma unroll
            for (int mt = 0; mt < 4; ++mt) {
                float pr[4], qr[4];
                #pragma unroll
                for (int ri = 0; ri < 4; ++ri) {
                    pr[ri] = sPQ[mt * 16 + g * 4 + ri];
                    qr[ri] = sPQ[64 + mt * 16 + g * 4 + ri];
                }
                #pragma unroll
                for (int tt = 0; tt < 2; ++tt) {
                    const int colL = (2 * w + tt) * 16 + li;   // 0..127 chunk-local
                    const float cs1 = CS1f[ch * 128 + colL];
                    const float k1v = K1f[ch * 128 + colL];
                    #pragma unroll
                    for (int ri = 0; ri < 4; ++ri) {
                        const float hv = pr[ri] * ha[tt][mt][ri] - qr[ri] * cs1 + k1v;
                        sH[(mt * 16 + g * 4 + ri) * HSTR + colL] = f2b(gelu_f(hv));
                    }
                }
            }
        }
        __syncthreads();
        #pragma unroll
        for (int ks = 0; ks < 4; ++ks) {           // K = 128 per chunk
            bf16x8 af[4];
            #pragma unroll
            for (int mt = 0; mt < 4; ++mt)
                af[mt] = ldfrag(&sH[(mt * 16 + li) * HSTR + ks * 32 + g * 8]);
            #pragma unroll
            for (int tt = 0; tt < 3; ++tt) {
                bf16x8 bf = ldfrag(&wf[O_W2 + (((3 * w + tt) * 24 + ch * 4 + ks) << 9) + l * 8]);
                #pragma unroll
                for (int mt = 0; mt < 4; ++mt) ma[tt][mt] = MFMA(af[mt], bf, ma[tt][mt]);
            }
        }
        __syncthreads();
    }

    // ---- x2 = x1 + mlp + b2 -> sB ----
    #pragma unroll
    for (int tt = 0; tt < 3; ++tt) {
        const int col = (3 * w + tt) * 16 + li;
        const float bv = b2[col];
        #pragma unroll
        for (int mt = 0; mt < 4; ++mt)
            #pragma unroll
            for (int ri = 0; ri < 4; ++ri) {
                const int o = (mt * 16 + g * 4 + ri) * 200 + col;
                sB[o] = f2b(ma[tt][mt][ri] + bv + b2f(sB[o]));
            }
    }
    __syncthreads();

    // ---- vectorized store (window reverse + roll back) ----
    #pragma unroll
    for (int i = 0; i < 12; ++i) {
        const int id = i * 256 + tid;
        const int c  = id >> 4;
        const int r  = (id >> 1) & 7;
        const int hf = id & 1;
        const int ohr = (wh * 8 + r + 4) & 127;
        const int owp = (ww * 8 + hf * 4 + 4) & 127;
        const int t0 = r * 8 + hf * 4;
        float4 v;
        v.x = b2f(sB[(t0 + 0) * 200 + c]);
        v.y = b2f(sB[(t0 + 1) * 200 + c]);
        v.z = b2f(sB[(t0 + 2) * 200 + c]);
        v.w = b2f(sB[(t0 + 3) * 200 + c]);
        *reinterpret_cast<float4*>(out + ((b * 192 + c) << 14) + (ohr << 7) + owp) = v;
    }
}

} // namespace

extern "C" void kernel_launch(void* const* d_in, const int* in_sizes, int n_in,
                              void* d_out, int out_size, void* d_ws, size_t ws_size,
                              hipStream_t stream) {
    (void)in_sizes; (void)n_in; (void)ws_size; (void)out_size;
    const float* x   = (const float*)d_in[0];
    const float* bt  = (const float*)d_in[1];
    const float* qw  = (const float*)d_in[2];
    const float* qb  = (const float*)d_in[3];
    const float* pw  = (const float*)d_in[4];
    const float* pb  = (const float*)d_in[5];
    const float* g1  = (const float*)d_in[6];
    const float* be1 = (const float*)d_in[7];
    const float* g2  = (const float*)d_in[8];
    const float* be2 = (const float*)d_in[9];
    const float* w1  = (const float*)d_in[10];
    const float* bb1 = (const float*)d_in[11];
    const float* w2  = (const float*)d_in[12];
    const float* bb2 = (const float*)d_in[13];

    unsigned short* wf = (unsigned short*)d_ws;
    float* fbuf = (float*)((char*)d_ws + (size_t)W_TOT * 2);

    convert_frag<<<(W_TOT + 255) / 256, 256, 0, stream>>>(qw, pw, w1, w2, g1, g2, wf);
    convert_vec<<<6, 256, 0, stream>>>(qw, qb, g1, be1, w1, bb1, g2, be2, fbuf);
    swin_mfma<<<NB * 256, 256, 0, stream>>>(x, bt, pb, bb2, wf, (float*)d_out);
}

// Round 11
// 445.974 us; speedup vs baseline: 1.1495x; 1.0148x over previous
//
#include <hip/hip_runtime.h>
#include <math.h>

namespace {

constexpr int NB   = 8;
constexpr int IMG  = 128;
constexpr float SCALE = 0.14433756729740643f; // 1/sqrt(48)

// frag-major bf16 weight buffer offsets (ushort elements)
constexpr int O_QKV = 0;          // 4*9*6*512   = 110592 (LN1-gamma folded)
constexpr int O_WP  = 110592;     // 4*12*2*512  =  49152 (per-head, k-padded to 64)
constexpr int O_W1  = 159744;     // 48*6*512    = 147456 (LN2-gamma folded)
constexpr int O_W2  = 307200;     // 12*24*512   = 147456
constexpr int W_TOT = 454656;     // ushorts -> float region at byte 909312
// float region: CS0[576], K0[576], CS1[768], K1[768]

constexpr int HSTR = 136;         // MLP hidden LDS stride (128 cols + pad)

typedef __bf16 bf16x8 __attribute__((ext_vector_type(8)));
typedef float  f32x4  __attribute__((ext_vector_type(4)));

__device__ __forceinline__ unsigned short f2b(float f) {
    union { __bf16 h; unsigned short u; } c;
    c.h = (__bf16)f;                      // native cvt, RTNE (absmax-verified r9)
    return c.u;
}
__device__ __forceinline__ float b2f(unsigned short h) {
    union { unsigned int u; float f; } a; a.u = ((unsigned int)h) << 16;
    return a.f;
}
__device__ __forceinline__ bf16x8 ldfrag(const unsigned short* p) {
    return *reinterpret_cast<const bf16x8*>(p);
}
__device__ __forceinline__ f32x4 MFMA(bf16x8 a, bf16x8 b, f32x4 c) {
    return __builtin_amdgcn_mfma_f32_16x16x32_bf16(a, b, c, 0, 0, 0);
}
__device__ __forceinline__ int token_region(int wh, int ww, int tok) {
    const int hh = wh * 8 + (tok >> 3);
    const int wp = ww * 8 + (tok & 7);
    const int hr = (hh < IMG - 8) ? 0 : ((hh < IMG - 4) ? 1 : 2);
    const int wr = (wp < IMG - 8) ? 0 : ((wp < IMG - 4) ? 1 : 2);
    return hr * 3 + wr;
}
__device__ __forceinline__ float gelu_f(float v) {
    float y = 1.5957691216057308f * (v + 0.044715f * v * v * v);
    y = fminf(fmaxf(y, -40.f), 40.f);
    const float e = __expf(y);
    const float t = (e - 1.f) * __builtin_amdgcn_rcpf(e + 1.f);
    return 0.5f * v * (1.f + t);
}
__device__ __forceinline__ void unpack8(uint4 r, float* v) {
    v[0] = b2f((unsigned short)(r.x & 0xFFFF)); v[1] = b2f((unsigned short)(r.x >> 16));
    v[2] = b2f((unsigned short)(r.y & 0xFFFF)); v[3] = b2f((unsigned short)(r.y >> 16));
    v[4] = b2f((unsigned short)(r.z & 0xFFFF)); v[5] = b2f((unsigned short)(r.z >> 16));
    v[6] = b2f((unsigned short)(r.w & 0xFFFF)); v[7] = b2f((unsigned short)(r.w >> 16));
}

// ---- weights -> bf16 frag-major (LN gammas folded into QKV / W1) ----
__global__ __launch_bounds__(256)
void convert_frag(const float* __restrict__ qkv_w, const float* __restrict__ proj_w,
                  const float* __restrict__ w1, const float* __restrict__ w2,
                  const float* __restrict__ n1g, const float* __restrict__ n2g,
                  unsigned short* __restrict__ wf)
{
    const int id = blockIdx.x * 256 + threadIdx.x;
    if (id >= W_TOT) return;
    float val;
    if (id < O_WP) {
        const int j = id & 7, l = (id >> 3) & 63, rem = id >> 9;
        const int ks = rem % 6, n = (rem / 6) % 9, h = rem / 54;
        const int k = ks * 32 + (l >> 4) * 8 + j;
        const int scol = n * 16 + (l & 15);
        const int col = (scol / 48) * 192 + h * 48 + scol % 48;
        val = qkv_w[k * 576 + col] * n1g[k];
    } else if (id < O_W1) {
        const int t = id - O_WP;
        const int j = t & 7, l = (t >> 3) & 63, rem = t >> 9;   // 0..95
        const int ks = rem % 2, tt = (rem / 2) % 12, h = rem / 24;
        const int k = ks * 32 + (l >> 4) * 8 + j;               // padded-d 0..63
        const int col = tt * 16 + (l & 15);
        val = (k < 48) ? proj_w[(h * 48 + k) * 192 + col] : 0.f;
    } else if (id < O_W2) {
        const int t = id - O_W1;
        const int j = t & 7, l = (t >> 3) & 63, rem = t >> 9;
        const int ks = rem % 6, n = rem / 6;
        const int k = ks * 32 + (l >> 4) * 8 + j;
        val = w1[k * 768 + n * 16 + (l & 15)] * n2g[k];
    } else {
        const int t = id - O_W2;
        const int j = t & 7, l = (t >> 3) & 63, rem = t >> 9;
        const int ks = rem % 24, n = rem / 24;
        const int k = ks * 32 + (l >> 4) * 8 + j;
        val = w2[k * 192 + n * 16 + (l & 15)];
    }
    wf[id] = f2b(val);
}

// ---- column sums + folded bias constants (fp32) ----
__global__ __launch_bounds__(256)
void convert_vec(const float* __restrict__ qkv_w, const float* __restrict__ qkv_b,
                 const float* __restrict__ n1g, const float* __restrict__ n1b,
                 const float* __restrict__ w1, const float* __restrict__ b1,
                 const float* __restrict__ n2g, const float* __restrict__ n2b,
                 float* __restrict__ fbuf)
{
    const int id = blockIdx.x * 256 + threadIdx.x;
    if (id < 576) {
        const int li = id & 15, n = (id >> 4) % 9, h = id / 144;
        const int scol = n * 16 + li;
        const int col = (scol / 48) * 192 + h * 48 + scol % 48;
        float cs = 0.f, k0 = 0.f;
        for (int c = 0; c < 192; ++c) {
            const float wv = qkv_w[c * 576 + col];
            cs += n1g[c] * wv; k0 += n1b[c] * wv;
        }
        fbuf[id] = cs;
        fbuf[576 + id] = k0 + qkv_b[col];
    } else if (id < 1344) {
        const int u = id - 576;
        float cs = 0.f, k1 = 0.f;
        for (int c = 0; c < 192; ++c) {
            const float wv = w1[c * 768 + u];
            cs += n2g[c] * wv; k1 += n2b[c] * wv;
        }
        fbuf[1152 + u] = cs;
        fbuf[1920 + u] = k1 + b1[u];
    }
}

// LN stats via intra-wave shuffles: sPQ[row]=rsig, sPQ[64+row]=rsig*mu
__device__ __forceinline__ void stats_pass(const unsigned short* src, float* sPQ, int tid)
{
    const int w = tid >> 6, l = tid & 63;
    const int srow = 16 * w + (l >> 2);
    const int sub = l & 3;
    const unsigned short* sp = src + srow * 200 + sub * 48;
    float s = 0.f, s2 = 0.f;
    #pragma unroll
    for (int i = 0; i < 6; ++i) {
        uint4 r = *reinterpret_cast<const uint4*>(sp + i * 8);
        float v[8]; unpack8(r, v);
        #pragma unroll
        for (int e = 0; e < 8; ++e) { s += v[e]; s2 += v[e] * v[e]; }
    }
    s  += __shfl_xor(s, 1);  s  += __shfl_xor(s, 2);
    s2 += __shfl_xor(s2, 1); s2 += __shfl_xor(s2, 2);
    if (sub == 0) {
        const float mu = s * (1.f / 192.f);
        const float ms = s2 * (1.f / 192.f);
        const float rsig = rsqrtf(ms - mu * mu + 1e-5f);
        sPQ[srow] = rsig;
        sPQ[64 + srow] = rsig * mu;
    }
}

// 3 waves/EU. Static unified-RF split must cover max_arch + max_acc <= ~170.
// Proj folded per-head: pa[12] lives in ACC regs across heads (no opk arch array)
// -> max_arch ~72 (P1), max_acc 96 (P1: qkv 48 + pa 48); MLP: 60 arch + 80 acc.
__global__ __launch_bounds__(256, 3)
void swin_mfma(const float* __restrict__ x,
               const float* __restrict__ bias_tab,
               const float* __restrict__ proj_b,
               const float* __restrict__ b2,
               const unsigned short* __restrict__ wf,
               float* __restrict__ out)
{
    __shared__ unsigned short sB[64 * 200];   // x -> x1 -> x2 (bf16)
    __shared__ unsigned short sH[13440];      // q[64][72] | k[64][72] | vt[48][88]; hidden[64][HSTR]
    __shared__ float sPQ[128];                // rsig | rsig*mu per row

    constexpr int Q0  = 0;
    constexpr int K0o = 4608;
    constexpr int VT0 = 9216;

    const float* CS0f = reinterpret_cast<const float*>(wf + W_TOT);
    const float* K0f  = CS0f + 576;
    const float* CS1f = CS0f + 1152;
    const float* K1f  = CS0f + 1920;

    const int tid = threadIdx.x;
    const int l   = tid & 63;
    const int w   = tid >> 6;
    const int g   = l >> 4;
    const int li  = l & 15;

    const int wid  = blockIdx.x;
    const int b    = wid >> 8;
    const int nwin = wid & 255;
    const int wh   = nwin >> 4, ww = nwin & 15;

    // ---- zero-pad q,k cols 48..63 (persist through all heads) ----
    #pragma unroll
    for (int i = 0; i < 8; ++i) {
        const int e = i * 256 + tid;           // < 2048
        const int a = e >> 10;
        const int r = (e & 1023) >> 4;
        const int c = 48 + (e & 15);
        sH[(a ? K0o : Q0) + r * 72 + c] = 0;
    }

    // ---- vectorized load of shifted window -> sB (bf16) ----
    #pragma unroll
    for (int i = 0; i < 12; ++i) {
        const int id = i * 256 + tid;          // 0..3071
        const int c  = id >> 4;
        const int r  = (id >> 1) & 7;
        const int hf = id & 1;
        const int ohr = (wh * 8 + r + 4) & 127;
        const int owp = (ww * 8 + hf * 4 + 4) & 127;
        const float4 v = *reinterpret_cast<const float4*>(
            x + ((b * 192 + c) << 14) + (ohr << 7) + owp);
        const int t0 = r * 8 + hf * 4;
        sB[(t0 + 0) * 200 + c] = f2b(v.x);
        sB[(t0 + 1) * 200 + c] = f2b(v.y);
        sB[(t0 + 2) * 200 + c] = f2b(v.z);
        sB[(t0 + 3) * 200 + c] = f2b(v.w);
    }
    __syncthreads();

    // ---- LN1 stats ----
    stats_pass(sB, sPQ, tid);
    __syncthreads();

    // ---- hoisted attention lane constants ----
    const int qtok = 16 * w + li;
    const int qy = qtok >> 3, qx = qtok & 7;
    const int rq = token_region(wh, ww, qtok);
    unsigned int maskb = 0;
    unsigned int bpack[4];
    #pragma unroll
    for (int mt = 0; mt < 4; ++mt) {
        unsigned int pk = 0;
        #pragma unroll
        for (int ri = 0; ri < 4; ++ri) {
            const int k = mt * 16 + g * 4 + ri;
            const int ky = k >> 3, kx = k & 7;
            pk |= (unsigned int)((qy - ky + 7) * 15 + (qx - kx + 7)) << (8 * ri);
            if (token_region(wh, ww, k) != rq) maskb |= 1u << (mt * 4 + ri);
        }
        bpack[mt] = pk;
    }

    // proj accumulator: rows 16w..16w+15 x 192 cols, ACC regs, lives across heads
    f32x4 pa[12];
    #pragma unroll
    for (int tt = 0; tt < 12; ++tt) pa[tt] = (f32x4)0.f;

    // ================= attention heads (proj folded per head) =================
    #pragma unroll
    for (int h = 0; h < 4; ++h) {
        // ---- P1: QKV GEMM (LN folded), shared-B scheme: wave w owns N-tiles {w, 4+w, 8(w0)} ----
        {
            f32x4 acc[3][4];
            #pragma unroll
            for (int tt = 0; tt < 3; ++tt)
                #pragma unroll
                for (int mt = 0; mt < 4; ++mt) acc[tt][mt] = (f32x4)0.f;
            #pragma unroll
            for (int ks = 0; ks < 6; ++ks) {
                bf16x8 af[4];
                #pragma unroll
                for (int mt = 0; mt < 4; ++mt)
                    af[mt] = ldfrag(&sB[(mt * 16 + li) * 200 + ks * 32 + g * 8]);
                #pragma unroll
                for (int tt = 0; tt < 3; ++tt) {
                    if (tt == 2 && w != 0) continue;
                    const int n = (tt == 2) ? 8 : w + tt * 4;
                    bf16x8 bf = ldfrag(&wf[O_QKV + (((h * 9 + n) * 6 + ks) << 9) + l * 8]);
                    #pragma unroll
                    for (int mt = 0; mt < 4; ++mt) acc[tt][mt] = MFMA(af[mt], bf, acc[tt][mt]);
                }
            }
            float csv[3], k0v[3];
            #pragma unroll
            for (int tt = 0; tt < 3; ++tt) {
                if (tt == 2 && w != 0) { csv[tt] = 0.f; k0v[tt] = 0.f; continue; }
                const int n = (tt == 2) ? 8 : w + tt * 4;
                csv[tt] = CS0f[(h * 9 + n) * 16 + li];
                k0v[tt] = K0f[(h * 9 + n) * 16 + li];
            }
            #pragma unroll
            for (int mt = 0; mt < 4; ++mt) {
                float pr[4], qr[4];
                #pragma unroll
                for (int ri = 0; ri < 4; ++ri) {
                    pr[ri] = sPQ[mt * 16 + g * 4 + ri];
                    qr[ri] = sPQ[64 + mt * 16 + g * 4 + ri];
                }
                #pragma unroll
                for (int tt = 0; tt < 3; ++tt) {
                    if (tt == 2 && w != 0) continue;
                    const int n = (tt == 2) ? 8 : w + tt * 4;
                    const int scol0 = n * 16;
                    const int arr = scol0 / 48;      // wave-uniform
                    const int d0 = scol0 - arr * 48; // d = d0 + li
                    float val[4];
                    #pragma unroll
                    for (int ri = 0; ri < 4; ++ri)
                        val[ri] = pr[ri] * acc[tt][mt][ri] - qr[ri] * csv[tt] + k0v[tt];
                    if (arr < 2) {
                        unsigned short* dst = &sH[arr ? K0o : Q0];
                        #pragma unroll
                        for (int ri = 0; ri < 4; ++ri)
                            dst[(mt * 16 + g * 4 + ri) * 72 + d0 + li] = f2b(val[ri]);
                    } else {
                        uint2 u;
                        u.x = (unsigned int)f2b(val[0]) | ((unsigned int)f2b(val[1]) << 16);
                        u.y = (unsigned int)f2b(val[2]) | ((unsigned int)f2b(val[3]) << 16);
                        *reinterpret_cast<uint2*>(&sH[VT0 + (d0 + li) * 88 + mt * 16 + g * 4]) = u;
                    }
                }
            }
        }
        __syncthreads();

        // ---- P2: QK^T + register softmax + PV + per-head proj into pa ----
        {
            f32x4 sc[4];
            #pragma unroll
            for (int mt = 0; mt < 4; ++mt) sc[mt] = (f32x4)0.f;
            #pragma unroll
            for (int ks = 0; ks < 2; ++ks) {
                bf16x8 bq = ldfrag(&sH[Q0 + qtok * 72 + ks * 32 + g * 8]);
                #pragma unroll
                for (int mt = 0; mt < 4; ++mt) {
                    bf16x8 ak = ldfrag(&sH[K0o + (mt * 16 + li) * 72 + ks * 32 + g * 8]);
                    sc[mt] = MFMA(ak, bq, sc[mt]);   // S^T = K @ Q^T
                }
            }
            float p[4][4];
            float m = -3.0e38f;
            #pragma unroll
            for (int mt = 0; mt < 4; ++mt)
                #pragma unroll
                for (int ri = 0; ri < 4; ++ri) {
                    const int bit = mt * 4 + ri;
                    const float bv = ((maskb >> bit) & 1u) ? -100.f
                        : bias_tab[h * 225 + ((bpack[mt] >> (8 * ri)) & 255u)];
                    const float s = sc[mt][ri] * SCALE + bv;
                    p[mt][ri] = s;
                    m = fmaxf(m, s);
                }
            m = fmaxf(m, __shfl_xor(m, 16));
            m = fmaxf(m, __shfl_xor(m, 32));
            float rs = 0.f;
            #pragma unroll
            for (int mt = 0; mt < 4; ++mt)
                #pragma unroll
                for (int ri = 0; ri < 4; ++ri) {
                    const float e = __expf(p[mt][ri] - m);
                    p[mt][ri] = e; rs += e;
                }
            rs += __shfl_xor(rs, 16);
            rs += __shfl_xor(rs, 32);
            const float rcp = __builtin_amdgcn_rcpf(rs);

            f32x4 oa[3];
            #pragma unroll
            for (int mt = 0; mt < 3; ++mt) oa[mt] = (f32x4)0.f;
            #pragma unroll
            for (int ks = 0; ks < 2; ++ks) {
                union { unsigned short us[8]; bf16x8 v; } bp;
                #pragma unroll
                for (int jj = 0; jj < 8; ++jj) {
                    const int srcLane = li + 16 * (2 * (g & 1) + (jj >> 2));
                    const float va = __shfl(p[ks * 2 + 0][jj & 3], srcLane);
                    const float vb = __shfl(p[ks * 2 + 1][jj & 3], srcLane);
                    bp.us[jj] = f2b((g >> 1) ? vb : va);
                }
                #pragma unroll
                for (int mt = 0; mt < 3; ++mt) {
                    bf16x8 av = ldfrag(&sH[VT0 + (mt * 16 + li) * 88 + ks * 32 + g * 8]);
                    oa[mt] = MFMA(av, bp.v, oa[mt]);  // out^T = Vt @ P^T
                }
            }
            // pack normalized attn-out^T (short-lived, same layout as r10's opk[h])
            unsigned int ok[6];
            #pragma unroll
            for (int mt = 0; mt < 3; ++mt) {
                ok[mt * 2 + 0] = (unsigned int)f2b(oa[mt][0] * rcp)
                               | ((unsigned int)f2b(oa[mt][1] * rcp) << 16);
                ok[mt * 2 + 1] = (unsigned int)f2b(oa[mt][2] * rcp)
                               | ((unsigned int)f2b(oa[mt][3] * rcp) << 16);
            }
            // assemble proj A-frags (r7-verified lane selection) and accumulate pa
            union { unsigned short us[8]; bf16x8 v; } a0, a1;
            #pragma unroll
            for (int j = 0; j < 8; ++j) {
                const int srcL = (((2 * g + (j >> 2)) & 3) << 4) + li;
                const int ih = (j & 3) >> 1;
                const int sh = 16 * (j & 1);
                const unsigned int v0 = __shfl(ok[0 + ih], srcL); // mt=0 (d 0..15)
                const unsigned int v1 = __shfl(ok[2 + ih], srcL); // mt=1 (d 16..31)
                const unsigned int v2 = __shfl(ok[4 + ih], srcL); // mt=2 (d 32..47)
                a0.us[j] = (unsigned short)((((g & 2) ? v1 : v0) >> sh) & 0xFFFFu);
                a1.us[j] = (g & 2) ? (unsigned short)0
                                   : (unsigned short)((v2 >> sh) & 0xFFFFu);
            }
            #pragma unroll
            for (int tt = 0; tt < 12; ++tt) {
                bf16x8 w0 = ldfrag(&wf[O_WP + ((h * 24 + tt * 2 + 0) << 9) + l * 8]);
                bf16x8 w1f = ldfrag(&wf[O_WP + ((h * 24 + tt * 2 + 1) << 9) + l * 8]);
                pa[tt] = MFMA(a0.v, w0, pa[tt]);
                pa[tt] = MFMA(a1.v, w1f, pa[tt]);
            }
        }
        __syncthreads();
    }

    // ---- x1 = x + proj + proj_b (RMW sB; each element owned by one thread) ----
    #pragma unroll
    for (int tt = 0; tt < 12; ++tt) {
        const int col = tt * 16 + li;
        const float pbv = proj_b[col];
        #pragma unroll
        for (int ri = 0; ri < 4; ++ri) {
            const int o = (16 * w + g * 4 + ri) * 200 + col;
            sB[o] = f2b(b2f(sB[o]) + pa[tt][ri] + pbv);
        }
    }
    __syncthreads();

    // ---- LN2 stats ----
    stats_pass(sB, sPQ, tid);
    __syncthreads();

    // ---- MLP (LN2 folded into W1), hidden chunks of 128 (6 chunks): acc peak 80 ----
    f32x4 ma[3][4];
    #pragma unroll
    for (int tt = 0; tt < 3; ++tt)
        #pragma unroll
        for (int mt = 0; mt < 4; ++mt) ma[tt][mt] = (f32x4)0.f;

    for (int ch = 0; ch < 6; ++ch) {
        {
            f32x4 ha[2][4];
            #pragma unroll
            for (int tt = 0; tt < 2; ++tt)
                #pragma unroll
                for (int mt = 0; mt < 4; ++mt) ha[tt][mt] = (f32x4)0.f;
            #pragma unroll
            for (int ks = 0; ks < 6; ++ks) {
                bf16x8 af[4];
                #pragma unroll
                for (int mt = 0; mt < 4; ++mt)
                    af[mt] = ldfrag(&sB[(mt * 16 + li) * 200 + ks * 32 + g * 8]);
                #pragma unroll
                for (int tt = 0; tt < 2; ++tt) {
                    bf16x8 bf = ldfrag(&wf[O_W1 + (((ch * 8 + 2 * w + tt) * 6 + ks) << 9) + l * 8]);
                    #pragma unroll
                    for (int mt = 0; mt < 4; ++mt) ha[tt][mt] = MFMA(af[mt], bf, ha[tt][mt]);
                }
            }
            #pragma unroll
            for (int mt = 0; mt < 4; ++mt) {
                float pr[4], qr[4];
                #pragma unroll
                for (int ri = 0; ri < 4; ++ri) {
                    pr[ri] = sPQ[mt * 16 + g * 4 + ri];
                    qr[ri] = sPQ[64 + mt * 16 + g * 4 + ri];
                }
                #pragma unroll
                for (int tt = 0; tt < 2; ++tt) {
                    const int colL = (2 * w + tt) * 16 + li;   // 0..127 chunk-local
                    const float cs1 = CS1f[ch * 128 + colL];
                    const float k1v = K1f[ch * 128 + colL];
                    #pragma unroll
                    for (int ri = 0; ri < 4; ++ri) {
                        const float hv = pr[ri] * ha[tt][mt][ri] - qr[ri] * cs1 + k1v;
                        sH[(mt * 16 + g * 4 + ri) * HSTR + colL] = f2b(gelu_f(hv));
                    }
                }
            }
        }
        __syncthreads();
        #pragma unroll
        for (int ks = 0; ks < 4; ++ks) {           // K = 128 per chunk
            bf16x8 af[4];
            #pragma unroll
            for (int mt = 0; mt < 4; ++mt)
                af[mt] = ldfrag(&sH[(mt * 16 + li) * HSTR + ks * 32 + g * 8]);
            #pragma unroll
            for (int tt = 0; tt < 3; ++tt) {
                bf16x8 bf = ldfrag(&wf[O_W2 + (((3 * w + tt) * 24 + ch * 4 + ks) << 9) + l * 8]);
                #pragma unroll
                for (int mt = 0; mt < 4; ++mt) ma[tt][mt] = MFMA(af[mt], bf, ma[tt][mt]);
            }
        }
        __syncthreads();
    }

    // ---- x2 = x1 + mlp + b2 -> sB ----
    #pragma unroll
    for (int tt = 0; tt < 3; ++tt) {
        const int col = (3 * w + tt) * 16 + li;
        const float bv = b2[col];
        #pragma unroll
        for (int mt = 0; mt < 4; ++mt)
            #pragma unroll
            for (int ri = 0; ri < 4; ++ri) {
                const int o = (mt * 16 + g * 4 + ri) * 200 + col;
                sB[o] = f2b(ma[tt][mt][ri] + bv + b2f(sB[o]));
            }
    }
    __syncthreads();

    // ---- vectorized store (window reverse + roll back) ----
    #pragma unroll
    for (int i = 0; i < 12; ++i) {
        const int id = i * 256 + tid;
        const int c  = id >> 4;
        const int r  = (id >> 1) & 7;
        const int hf = id & 1;
        const int ohr = (wh * 8 + r + 4) & 127;
        const int owp = (ww * 8 + hf * 4 + 4) & 127;
        const int t0 = r * 8 + hf * 4;
        float4 v;
        v.x = b2f(sB[(t0 + 0) * 200 + c]);
        v.y = b2f(sB[(t0 + 1) * 200 + c]);
        v.z = b2f(sB[(t0 + 2) * 200 + c]);
        v.w = b2f(sB[(t0 + 3) * 200 + c]);
        *reinterpret_cast<float4*>(out + ((b * 192 + c) << 14) + (ohr << 7) + owp) = v;
    }
}

} // namespace

extern "C" void kernel_launch(void* const* d_in, const int* in_sizes, int n_in,
                              void* d_out, int out_size, void* d_ws, size_t ws_size,
                              hipStream_t stream) {
    (void)in_sizes; (void)n_in; (void)ws_size; (void)out_size;
    const float* x   = (const float*)d_in[0];
    const float* bt  = (const float*)d_in[1];
    const float* qw  = (const float*)d_in[2];
    const float* qb  = (const float*)d_in[3];
    const float* pw  = (const float*)d_in[4];
    const float* pb  = (const float*)d_in[5];
    const float* g1  = (const float*)d_in[6];
    const float* be1 = (const float*)d_in[7];
    const float* g2  = (const float*)d_in[8];
    const float* be2 = (const float*)d_in[9];
    const float* w1  = (const float*)d_in[10];
    const float* bb1 = (const float*)d_in[11];
    const float* w2  = (const float*)d_in[12];
    const float* bb2 = (const float*)d_in[13];

    unsigned short* wf = (unsigned short*)d_ws;
    float* fbuf = (float*)((char*)d_ws + (size_t)W_TOT * 2);

    convert_frag<<<(W_TOT + 255) / 256, 256, 0, stream>>>(qw, pw, w1, w2, g1, g2, wf);
    convert_vec<<<6, 256, 0, stream>>>(qw, qb, g1, be1, w1, bb1, g2, be2, fbuf);
    swin_mfma<<<NB * 256, 256, 0, stream>>>(x, bt, pb, bb2, wf, (float*)d_out);
}

// Round 12
// 392.891 us; speedup vs baseline: 1.3048x; 1.1351x over previous
//
#include <hip/hip_runtime.h>
#include <math.h>

namespace {

constexpr int NB   = 8;
constexpr int IMG  = 128;
constexpr float SCALE = 0.14433756729740643f; // 1/sqrt(48)

// frag-major bf16 weight buffer offsets (ushort elements)
constexpr int O_QKV = 0;          // 4*9*6*512   = 110592 (LN1-gamma folded)
constexpr int O_WP  = 110592;     // 4*12*2*512  =  49152 (per-head, k-padded to 64)
constexpr int O_W1  = 159744;     // 48*6*512    = 147456 (LN2-gamma folded)
constexpr int O_W2  = 307200;     // 12*24*512   = 147456
constexpr int W_TOT = 454656;     // ushorts -> float region at byte 909312
// float region: CS0[576], K0[576], CS1[768], K1[768]

constexpr int HSTR = 136;         // MLP hidden LDS stride (128 cols + pad)

typedef __bf16 bf16x8 __attribute__((ext_vector_type(8)));
typedef float  f32x4  __attribute__((ext_vector_type(4)));

// sB bank swizzle: XOR cols by ((row>>4)&3)*8 ushorts (16B units).
// - scalar token-stride-4 accesses (x load/store epilogues): 8-way -> 2-way (free)
// - all frag reads (row = mt*16+li): row>>4 == mt, constant per instr -> no penalty
// - XOR stays within aligned 32-col blocks (192 = 6*32), preserves 16B alignment
__device__ __forceinline__ int sbx(int row, int col) {
    return row * 200 + (col ^ (((row >> 4) & 3) << 3));
}

__device__ __forceinline__ unsigned short f2b(float f) {
    union { __bf16 h; unsigned short u; } c;
    c.h = (__bf16)f;                      // native cvt, RTNE (absmax-verified r9)
    return c.u;
}
__device__ __forceinline__ float b2f(unsigned short h) {
    union { unsigned int u; float f; } a; a.u = ((unsigned int)h) << 16;
    return a.f;
}
__device__ __forceinline__ bf16x8 ldfrag(const unsigned short* p) {
    return *reinterpret_cast<const bf16x8*>(p);
}
__device__ __forceinline__ f32x4 MFMA(bf16x8 a, bf16x8 b, f32x4 c) {
    return __builtin_amdgcn_mfma_f32_16x16x32_bf16(a, b, c, 0, 0, 0);
}
__device__ __forceinline__ int token_region(int wh, int ww, int tok) {
    const int hh = wh * 8 + (tok >> 3);
    const int wp = ww * 8 + (tok & 7);
    const int hr = (hh < IMG - 8) ? 0 : ((hh < IMG - 4) ? 1 : 2);
    const int wr = (wp < IMG - 8) ? 0 : ((wp < IMG - 4) ? 1 : 2);
    return hr * 3 + wr;
}
__device__ __forceinline__ float gelu_f(float v) {
    float y = 1.5957691216057308f * (v + 0.044715f * v * v * v);
    y = fminf(fmaxf(y, -40.f), 40.f);
    const float e = __expf(y);
    const float t = (e - 1.f) * __builtin_amdgcn_rcpf(e + 1.f);
    return 0.5f * v * (1.f + t);
}
__device__ __forceinline__ void unpack8(uint4 r, float* v) {
    v[0] = b2f((unsigned short)(r.x & 0xFFFF)); v[1] = b2f((unsigned short)(r.x >> 16));
    v[2] = b2f((unsigned short)(r.y & 0xFFFF)); v[3] = b2f((unsigned short)(r.y >> 16));
    v[4] = b2f((unsigned short)(r.z & 0xFFFF)); v[5] = b2f((unsigned short)(r.z >> 16));
    v[6] = b2f((unsigned short)(r.w & 0xFFFF)); v[7] = b2f((unsigned short)(r.w >> 16));
}

// ---- weights -> bf16 frag-major (LN gammas folded into QKV / W1) ----
__global__ __launch_bounds__(256)
void convert_frag(const float* __restrict__ qkv_w, const float* __restrict__ proj_w,
                  const float* __restrict__ w1, const float* __restrict__ w2,
                  const float* __restrict__ n1g, const float* __restrict__ n2g,
                  unsigned short* __restrict__ wf)
{
    const int id = blockIdx.x * 256 + threadIdx.x;
    if (id >= W_TOT) return;
    float val;
    if (id < O_WP) {
        const int j = id & 7, l = (id >> 3) & 63, rem = id >> 9;
        const int ks = rem % 6, n = (rem / 6) % 9, h = rem / 54;
        const int k = ks * 32 + (l >> 4) * 8 + j;
        const int scol = n * 16 + (l & 15);
        const int col = (scol / 48) * 192 + h * 48 + scol % 48;
        val = qkv_w[k * 576 + col] * n1g[k];
    } else if (id < O_W1) {
        const int t = id - O_WP;
        const int j = t & 7, l = (t >> 3) & 63, rem = t >> 9;   // 0..95
        const int ks = rem % 2, tt = (rem / 2) % 12, h = rem / 24;
        const int k = ks * 32 + (l >> 4) * 8 + j;               // padded-d 0..63
        const int col = tt * 16 + (l & 15);
        val = (k < 48) ? proj_w[(h * 48 + k) * 192 + col] : 0.f;
    } else if (id < O_W2) {
        const int t = id - O_W1;
        const int j = t & 7, l = (t >> 3) & 63, rem = t >> 9;
        const int ks = rem % 6, n = rem / 6;
        const int k = ks * 32 + (l >> 4) * 8 + j;
        val = w1[k * 768 + n * 16 + (l & 15)] * n2g[k];
    } else {
        const int t = id - O_W2;
        const int j = t & 7, l = (t >> 3) & 63, rem = t >> 9;
        const int ks = rem % 24, n = rem / 24;
        const int k = ks * 32 + (l >> 4) * 8 + j;
        val = w2[k * 192 + n * 16 + (l & 15)];
    }
    wf[id] = f2b(val);
}

// ---- column sums + folded bias constants (fp32) ----
__global__ __launch_bounds__(256)
void convert_vec(const float* __restrict__ qkv_w, const float* __restrict__ qkv_b,
                 const float* __restrict__ n1g, const float* __restrict__ n1b,
                 const float* __restrict__ w1, const float* __restrict__ b1,
                 const float* __restrict__ n2g, const float* __restrict__ n2b,
                 float* __restrict__ fbuf)
{
    const int id = blockIdx.x * 256 + threadIdx.x;
    if (id < 576) {
        const int li = id & 15, n = (id >> 4) % 9, h = id / 144;
        const int scol = n * 16 + li;
        const int col = (scol / 48) * 192 + h * 48 + scol % 48;
        float cs = 0.f, k0 = 0.f;
        for (int c = 0; c < 192; ++c) {
            const float wv = qkv_w[c * 576 + col];
            cs += n1g[c] * wv; k0 += n1b[c] * wv;
        }
        fbuf[id] = cs;
        fbuf[576 + id] = k0 + qkv_b[col];
    } else if (id < 1344) {
        const int u = id - 576;
        float cs = 0.f, k1 = 0.f;
        for (int c = 0; c < 192; ++c) {
            const float wv = w1[c * 768 + u];
            cs += n2g[c] * wv; k1 += n2b[c] * wv;
        }
        fbuf[1152 + u] = cs;
        fbuf[1920 + u] = k1 + b1[u];
    }
}

// LN stats via intra-wave shuffles: sPQ[row]=rsig, sPQ[64+row]=rsig*mu
__device__ __forceinline__ void stats_pass(const unsigned short* src, float* sPQ, int tid)
{
    const int w = tid >> 6, l = tid & 63;
    const int srow = 16 * w + (l >> 2);
    const int sub = l & 3;
    float s = 0.f, s2 = 0.f;
    #pragma unroll
    for (int i = 0; i < 6; ++i) {
        uint4 r = *reinterpret_cast<const uint4*>(&src[sbx(srow, sub * 48 + i * 8)]);
        float v[8]; unpack8(r, v);
        #pragma unroll
        for (int e = 0; e < 8; ++e) { s += v[e]; s2 += v[e] * v[e]; }
    }
    s  += __shfl_xor(s, 1);  s  += __shfl_xor(s, 2);
    s2 += __shfl_xor(s2, 1); s2 += __shfl_xor(s2, 2);
    if (sub == 0) {
        const float mu = s * (1.f / 192.f);
        const float ms = s2 * (1.f / 192.f);
        const float rsig = rsqrtf(ms - mu * mu + 1e-5f);
        sPQ[srow] = rsig;
        sPQ[64 + srow] = rsig * mu;
    }
}

__global__ __launch_bounds__(256, 3)
void swin_mfma(const float* __restrict__ x,
               const float* __restrict__ bias_tab,
               const float* __restrict__ proj_b,
               const float* __restrict__ b2,
               const unsigned short* __restrict__ wf,
               float* __restrict__ out)
{
    __shared__ unsigned short sB[64 * 200];   // x -> x1 -> x2 (bf16, col-swizzled via sbx)
    __shared__ unsigned short sH[13440];      // q[64][72] | k[64][72] | vt[48][88]; hidden[64][HSTR]
    __shared__ float sPQ[128];                // rsig | rsig*mu per row

    constexpr int Q0  = 0;
    constexpr int K0o = 4608;
    constexpr int VT0 = 9216;

    const float* CS0f = reinterpret_cast<const float*>(wf + W_TOT);
    const float* K0f  = CS0f + 576;
    const float* CS1f = CS0f + 1152;
    const float* K1f  = CS0f + 1920;

    const int tid = threadIdx.x;
    const int l   = tid & 63;
    const int w   = tid >> 6;
    const int g   = l >> 4;
    const int li  = l & 15;

    // XCD-locality remap: default dispatch round-robins blockIdx across the 8 XCDs
    // (m09). Map blockIdx%8 -> image, blockIdx/8 -> window, so each XCD owns one
    // full image: W/H-adjacent windows share an L2 -> their 32B half-lines of x
    // reads and out writes merge (fixes the 2x FETCH/WRITE fragmentation).
    const int wid  = ((blockIdx.x & 7) << 8) | (blockIdx.x >> 3);
    const int b    = wid >> 8;
    const int nwin = wid & 255;
    const int wh   = nwin >> 4, ww = nwin & 15;

    // ---- zero-pad q,k cols 48..63 (persist through all heads) ----
    #pragma unroll
    for (int i = 0; i < 8; ++i) {
        const int e = i * 256 + tid;           // < 2048
        const int a = e >> 10;
        const int r = (e & 1023) >> 4;
        const int c = 48 + (e & 15);
        sH[(a ? K0o : Q0) + r * 72 + c] = 0;
    }

    // ---- vectorized load of shifted window -> sB (bf16) ----
    #pragma unroll
    for (int i = 0; i < 12; ++i) {
        const int id = i * 256 + tid;          // 0..3071
        const int c  = id >> 4;
        const int r  = (id >> 1) & 7;
        const int hf = id & 1;
        const int ohr = (wh * 8 + r + 4) & 127;
        const int owp = (ww * 8 + hf * 4 + 4) & 127;
        const float4 v = *reinterpret_cast<const float4*>(
            x + ((b * 192 + c) << 14) + (ohr << 7) + owp);
        const int t0 = r * 8 + hf * 4;
        sB[sbx(t0 + 0, c)] = f2b(v.x);
        sB[sbx(t0 + 1, c)] = f2b(v.y);
        sB[sbx(t0 + 2, c)] = f2b(v.z);
        sB[sbx(t0 + 3, c)] = f2b(v.w);
    }
    __syncthreads();

    // ---- LN1 stats ----
    stats_pass(sB, sPQ, tid);
    __syncthreads();

    // ---- hoisted attention lane constants ----
    const int qtok = 16 * w + li;
    const int qy = qtok >> 3, qx = qtok & 7;
    const int rq = token_region(wh, ww, qtok);
    unsigned int maskb = 0;
    unsigned int bpack[4];
    #pragma unroll
    for (int mt = 0; mt < 4; ++mt) {
        unsigned int pk = 0;
        #pragma unroll
        for (int ri = 0; ri < 4; ++ri) {
            const int k = mt * 16 + g * 4 + ri;
            const int ky = k >> 3, kx = k & 7;
            pk |= (unsigned int)((qy - ky + 7) * 15 + (qx - kx + 7)) << (8 * ri);
            if (token_region(wh, ww, k) != rq) maskb |= 1u << (mt * 4 + ri);
        }
        bpack[mt] = pk;
    }

    // proj accumulator: rows 16w..16w+15 x 192 cols, ACC regs, lives across heads
    f32x4 pa[12];
    #pragma unroll
    for (int tt = 0; tt < 12; ++tt) pa[tt] = (f32x4)0.f;

    // ================= attention heads (proj folded per head) =================
    #pragma unroll
    for (int h = 0; h < 4; ++h) {
        // ---- P1: QKV GEMM (LN folded), shared-B scheme: wave w owns N-tiles {w, 4+w, 8(w0)} ----
        {
            f32x4 acc[3][4];
            #pragma unroll
            for (int tt = 0; tt < 3; ++tt)
                #pragma unroll
                for (int mt = 0; mt < 4; ++mt) acc[tt][mt] = (f32x4)0.f;
            #pragma unroll
            for (int ks = 0; ks < 6; ++ks) {
                bf16x8 af[4];
                #pragma unroll
                for (int mt = 0; mt < 4; ++mt)
                    af[mt] = ldfrag(&sB[sbx(mt * 16 + li, ks * 32 + g * 8)]);
                #pragma unroll
                for (int tt = 0; tt < 3; ++tt) {
                    if (tt == 2 && w != 0) continue;
                    const int n = (tt == 2) ? 8 : w + tt * 4;
                    bf16x8 bf = ldfrag(&wf[O_QKV + (((h * 9 + n) * 6 + ks) << 9) + l * 8]);
                    #pragma unroll
                    for (int mt = 0; mt < 4; ++mt) acc[tt][mt] = MFMA(af[mt], bf, acc[tt][mt]);
                }
            }
            float csv[3], k0v[3];
            #pragma unroll
            for (int tt = 0; tt < 3; ++tt) {
                if (tt == 2 && w != 0) { csv[tt] = 0.f; k0v[tt] = 0.f; continue; }
                const int n = (tt == 2) ? 8 : w + tt * 4;
                csv[tt] = CS0f[(h * 9 + n) * 16 + li];
                k0v[tt] = K0f[(h * 9 + n) * 16 + li];
            }
            #pragma unroll
            for (int mt = 0; mt < 4; ++mt) {
                float pr[4], qr[4];
                #pragma unroll
                for (int ri = 0; ri < 4; ++ri) {
                    pr[ri] = sPQ[mt * 16 + g * 4 + ri];
                    qr[ri] = sPQ[64 + mt * 16 + g * 4 + ri];
                }
                #pragma unroll
                for (int tt = 0; tt < 3; ++tt) {
                    if (tt == 2 && w != 0) continue;
                    const int n = (tt == 2) ? 8 : w + tt * 4;
                    const int scol0 = n * 16;
                    const int arr = scol0 / 48;      // wave-uniform
                    const int d0 = scol0 - arr * 48; // d = d0 + li
                    float val[4];
                    #pragma unroll
                    for (int ri = 0; ri < 4; ++ri)
                        val[ri] = pr[ri] * acc[tt][mt][ri] - qr[ri] * csv[tt] + k0v[tt];
                    if (arr < 2) {
                        unsigned short* dst = &sH[arr ? K0o : Q0];
                        #pragma unroll
                        for (int ri = 0; ri < 4; ++ri)
                            dst[(mt * 16 + g * 4 + ri) * 72 + d0 + li] = f2b(val[ri]);
                    } else {
                        uint2 u;
                        u.x = (unsigned int)f2b(val[0]) | ((unsigned int)f2b(val[1]) << 16);
                        u.y = (unsigned int)f2b(val[2]) | ((unsigned int)f2b(val[3]) << 16);
                        *reinterpret_cast<uint2*>(&sH[VT0 + (d0 + li) * 88 + mt * 16 + g * 4]) = u;
                    }
                }
            }
        }
        __syncthreads();

        // ---- P2: QK^T + register softmax + PV + per-head proj into pa ----
        {
            f32x4 sc[4];
            #pragma unroll
            for (int mt = 0; mt < 4; ++mt) sc[mt] = (f32x4)0.f;
            #pragma unroll
            for (int ks = 0; ks < 2; ++ks) {
                bf16x8 bq = ldfrag(&sH[Q0 + qtok * 72 + ks * 32 + g * 8]);
                #pragma unroll
                for (int mt = 0; mt < 4; ++mt) {
                    bf16x8 ak = ldfrag(&sH[K0o + (mt * 16 + li) * 72 + ks * 32 + g * 8]);
                    sc[mt] = MFMA(ak, bq, sc[mt]);   // S^T = K @ Q^T
                }
            }
            float p[4][4];
            float m = -3.0e38f;
            #pragma unroll
            for (int mt = 0; mt < 4; ++mt)
                #pragma unroll
                for (int ri = 0; ri < 4; ++ri) {
                    const int bit = mt * 4 + ri;
                    const float bv = ((maskb >> bit) & 1u) ? -100.f
                        : bias_tab[h * 225 + ((bpack[mt] >> (8 * ri)) & 255u)];
                    const float s = sc[mt][ri] * SCALE + bv;
                    p[mt][ri] = s;
                    m = fmaxf(m, s);
                }
            m = fmaxf(m, __shfl_xor(m, 16));
            m = fmaxf(m, __shfl_xor(m, 32));
            float rs = 0.f;
            #pragma unroll
            for (int mt = 0; mt < 4; ++mt)
                #pragma unroll
                for (int ri = 0; ri < 4; ++ri) {
                    const float e = __expf(p[mt][ri] - m);
                    p[mt][ri] = e; rs += e;
                }
            rs += __shfl_xor(rs, 16);
            rs += __shfl_xor(rs, 32);
            const float rcp = __builtin_amdgcn_rcpf(rs);

            f32x4 oa[3];
            #pragma unroll
            for (int mt = 0; mt < 3; ++mt) oa[mt] = (f32x4)0.f;
            #pragma unroll
            for (int ks = 0; ks < 2; ++ks) {
                union { unsigned short us[8]; bf16x8 v; } bp;
                #pragma unroll
                for (int jj = 0; jj < 8; ++jj) {
                    const int srcLane = li + 16 * (2 * (g & 1) + (jj >> 2));
                    const float va = __shfl(p[ks * 2 + 0][jj & 3], srcLane);
                    const float vb = __shfl(p[ks * 2 + 1][jj & 3], srcLane);
                    bp.us[jj] = f2b((g >> 1) ? vb : va);
                }
                #pragma unroll
                for (int mt = 0; mt < 3; ++mt) {
                    bf16x8 av = ldfrag(&sH[VT0 + (mt * 16 + li) * 88 + ks * 32 + g * 8]);
                    oa[mt] = MFMA(av, bp.v, oa[mt]);  // out^T = Vt @ P^T
                }
            }
            // pack normalized attn-out^T (short-lived)
            unsigned int ok[6];
            #pragma unroll
            for (int mt = 0; mt < 3; ++mt) {
                ok[mt * 2 + 0] = (unsigned int)f2b(oa[mt][0] * rcp)
                               | ((unsigned int)f2b(oa[mt][1] * rcp) << 16);
                ok[mt * 2 + 1] = (unsigned int)f2b(oa[mt][2] * rcp)
                               | ((unsigned int)f2b(oa[mt][3] * rcp) << 16);
            }
            // assemble proj A-frags (r7-verified lane selection) and accumulate pa
            union { unsigned short us[8]; bf16x8 v; } a0, a1;
            #pragma unroll
            for (int j = 0; j < 8; ++j) {
                const int srcL = (((2 * g + (j >> 2)) & 3) << 4) + li;
                const int ih = (j & 3) >> 1;
                const int sh = 16 * (j & 1);
                const unsigned int v0 = __shfl(ok[0 + ih], srcL); // mt=0 (d 0..15)
                const unsigned int v1 = __shfl(ok[2 + ih], srcL); // mt=1 (d 16..31)
                const unsigned int v2 = __shfl(ok[4 + ih], srcL); // mt=2 (d 32..47)
                a0.us[j] = (unsigned short)((((g & 2) ? v1 : v0) >> sh) & 0xFFFFu);
                a1.us[j] = (g & 2) ? (unsigned short)0
                                   : (unsigned short)((v2 >> sh) & 0xFFFFu);
            }
            #pragma unroll
            for (int tt = 0; tt < 12; ++tt) {
                bf16x8 w0 = ldfrag(&wf[O_WP + ((h * 24 + tt * 2 + 0) << 9) + l * 8]);
                bf16x8 w1f = ldfrag(&wf[O_WP + ((h * 24 + tt * 2 + 1) << 9) + l * 8]);
                pa[tt] = MFMA(a0.v, w0, pa[tt]);
                pa[tt] = MFMA(a1.v, w1f, pa[tt]);
            }
        }
        __syncthreads();
    }

    // ---- x1 = x + proj + proj_b (RMW sB; each element owned by one thread) ----
    #pragma unroll
    for (int tt = 0; tt < 12; ++tt) {
        const int col = tt * 16 + li;
        const float pbv = proj_b[col];
        #pragma unroll
        for (int ri = 0; ri < 4; ++ri) {
            const int o = sbx(16 * w + g * 4 + ri, col);
            sB[o] = f2b(b2f(sB[o]) + pa[tt][ri] + pbv);
        }
    }
    __syncthreads();

    // ---- LN2 stats ----
    stats_pass(sB, sPQ, tid);
    __syncthreads();

    // ---- MLP (LN2 folded into W1), hidden chunks of 128 (6 chunks): acc peak 80 ----
    f32x4 ma[3][4];
    #pragma unroll
    for (int tt = 0; tt < 3; ++tt)
        #pragma unroll
        for (int mt = 0; mt < 4; ++mt) ma[tt][mt] = (f32x4)0.f;

    for (int ch = 0; ch < 6; ++ch) {
        {
            f32x4 ha[2][4];
            #pragma unroll
            for (int tt = 0; tt < 2; ++tt)
                #pragma unroll
                for (int mt = 0; mt < 4; ++mt) ha[tt][mt] = (f32x4)0.f;
            #pragma unroll
            for (int ks = 0; ks < 6; ++ks) {
                bf16x8 af[4];
                #pragma unroll
                for (int mt = 0; mt < 4; ++mt)
                    af[mt] = ldfrag(&sB[sbx(mt * 16 + li, ks * 32 + g * 8)]);
                #pragma unroll
                for (int tt = 0; tt < 2; ++tt) {
                    bf16x8 bf = ldfrag(&wf[O_W1 + (((ch * 8 + 2 * w + tt) * 6 + ks) << 9) + l * 8]);
                    #pragma unroll
                    for (int mt = 0; mt < 4; ++mt) ha[tt][mt] = MFMA(af[mt], bf, ha[tt][mt]);
                }
            }
            #pragma unroll
            for (int mt = 0; mt < 4; ++mt) {
                float pr[4], qr[4];
                #pragma unroll
                for (int ri = 0; ri < 4; ++ri) {
                    pr[ri] = sPQ[mt * 16 + g * 4 + ri];
                    qr[ri] = sPQ[64 + mt * 16 + g * 4 + ri];
                }
                #pragma unroll
                for (int tt = 0; tt < 2; ++tt) {
                    const int colL = (2 * w + tt) * 16 + li;   // 0..127 chunk-local
                    const float cs1 = CS1f[ch * 128 + colL];
                    const float k1v = K1f[ch * 128 + colL];
                    #pragma unroll
                    for (int ri = 0; ri < 4; ++ri) {
                        const float hv = pr[ri] * ha[tt][mt][ri] - qr[ri] * cs1 + k1v;
                        sH[(mt * 16 + g * 4 + ri) * HSTR + colL] = f2b(gelu_f(hv));
                    }
                }
            }
        }
        __syncthreads();
        #pragma unroll
        for (int ks = 0; ks < 4; ++ks) {           // K = 128 per chunk
            bf16x8 af[4];
            #pragma unroll
            for (int mt = 0; mt < 4; ++mt)
                af[mt] = ldfrag(&sH[(mt * 16 + li) * HSTR + ks * 32 + g * 8]);
            #pragma unroll
            for (int tt = 0; tt < 3; ++tt) {
                bf16x8 bf = ldfrag(&wf[O_W2 + (((3 * w + tt) * 24 + ch * 4 + ks) << 9) + l * 8]);
                #pragma unroll
                for (int mt = 0; mt < 4; ++mt) ma[tt][mt] = MFMA(af[mt], bf, ma[tt][mt]);
            }
        }
        __syncthreads();
    }

    // ---- x2 = x1 + mlp + b2 -> sB ----
    #pragma unroll
    for (int tt = 0; tt < 3; ++tt) {
        const int col = (3 * w + tt) * 16 + li;
        const float bv = b2[col];
        #pragma unroll
        for (int mt = 0; mt < 4; ++mt)
            #pragma unroll
            for (int ri = 0; ri < 4; ++ri) {
                const int o = sbx(mt * 16 + g * 4 + ri, col);
                sB[o] = f2b(ma[tt][mt][ri] + bv + b2f(sB[o]));
            }
    }
    __syncthreads();

    // ---- vectorized store (window reverse + roll back) ----
    #pragma unroll
    for (int i = 0; i < 12; ++i) {
        const int id = i * 256 + tid;
        const int c  = id >> 4;
        const int r  = (id >> 1) & 7;
        const int hf = id & 1;
        const int ohr = (wh * 8 + r + 4) & 127;
        const int owp = (ww * 8 + hf * 4 + 4) & 127;
        const int t0 = r * 8 + hf * 4;
        float4 v;
        v.x = b2f(sB[sbx(t0 + 0, c)]);
        v.y = b2f(sB[sbx(t0 + 1, c)]);
        v.z = b2f(sB[sbx(t0 + 2, c)]);
        v.w = b2f(sB[sbx(t0 + 3, c)]);
        *reinterpret_cast<float4*>(out + ((b * 192 + c) << 14) + (ohr << 7) + owp) = v;
    }
}

} // namespace

extern "C" void kernel_launch(void* const* d_in, const int* in_sizes, int n_in,
                              void* d_out, int out_size, void* d_ws, size_t ws_size,
                              hipStream_t stream) {
    (void)in_sizes; (void)n_in; (void)ws_size; (void)out_size;
    const float* x   = (const float*)d_in[0];
    const float* bt  = (const float*)d_in[1];
    const float* qw  = (const float*)d_in[2];
    const float* qb  = (const float*)d_in[3];
    const float* pw  = (const float*)d_in[4];
    const float* pb  = (const float*)d_in[5];
    const float* g1  = (const float*)d_in[6];
    const float* be1 = (const float*)d_in[7];
    const float* g2  = (const float*)d_in[8];
    const float* be2 = (const float*)d_in[9];
    const float* w1  = (const float*)d_in[10];
    const float* bb1 = (const float*)d_in[11];
    const float* w2  = (const float*)d_in[12];
    const float* bb2 = (const float*)d_in[13];

    unsigned short* wf = (unsigned short*)d_ws;
    float* fbuf = (float*)((char*)d_ws + (size_t)W_TOT * 2);

    convert_frag<<<(W_TOT + 255) / 256, 256, 0, stream>>>(qw, pw, w1, w2, g1, g2, wf);
    convert_vec<<<6, 256, 0, stream>>>(qw, qb, g1, be1, w1, bb1, g2, be2, fbuf);
    swin_mfma<<<NB * 256, 256, 0, stream>>>(x, bt, pb, bb2, wf, (float*)d_out);
}